// Round 10
// baseline (192.375 us; speedup 1.0000x reference)
//
#include <hip/hip_runtime.h>
#include <hip/hip_bf16.h>
#include <cstdint>

#define BATCH 4096
#define INF   1024
#define OUTF  1024
#define LCH   12
#define KTOT  (INF*LCH)       // 12288
#define NKT   128             // K-tiles of 96
#define BK    96
#define BM    256
#define BN    128
#define THREADS 512
#define ASZ (12*256*8)        // 24576 ushorts = 48 KB per A tile
#define BSZ (12*128*8)        // 12288 ushorts = 24 KB per B tile

#define WTT_BYTES ((size_t)OUTF * KTOT * 2)            // 25165824
#define AT_BYTES  ((size_t)BATCH * KTOT * 2)           // 100663296
#define OUT_BYTES ((size_t)BATCH * OUTF * 4)           // 16777216

typedef __bf16 bf16x8 __attribute__((ext_vector_type(8)));
typedef float  f32x4  __attribute__((ext_vector_type(4)));
typedef float  f32x16 __attribute__((ext_vector_type(16)));
typedef unsigned long long ull;
typedef unsigned short us;

struct alignas(16) U2 { ull x, y; };

__device__ __forceinline__ us f2bf(float f) {
  unsigned int u = __builtin_bit_cast(unsigned int, f);
  u += 0x7FFFu + ((u >> 16) & 1u);
  return (us)(u >> 16);
}

__device__ __forceinline__ void async_copy16(const void* g, void* l) {
  __builtin_amdgcn_global_load_lds(
      (const __attribute__((address_space(1))) unsigned int*)g,
      (__attribute__((address_space(3))) unsigned int*)l,
      16, 0, 0);
}

#define WAIT_VM(N) do {                                            \
  asm volatile("s_waitcnt vmcnt(" #N ")" ::: "memory");            \
  __builtin_amdgcn_sched_barrier(0);                               \
} while (0)

#define WAIT_LGKM0() do {                                          \
  asm volatile("s_waitcnt lgkmcnt(0)" ::: "memory");               \
  __builtin_amdgcn_sched_barrier(0);                               \
} while (0)

#define BARRIER() __builtin_amdgcn_s_barrier()

// compute the 12 bf16 channels (11 spline + base/x) for one feature value
__device__ __forceinline__ void basis12(float xx, ull W[3]) {
  float u  = fmaf(xx, 4.0f, 7.0f);       // in (3,11); x in (-1,1)
  float fm = floorf(u);
  int   mi = (int)fm;                    // 3..10
  float t  = u - fm;
  float s  = 1.0f - t;
  float t2 = t * t, t3 = t2 * t;
  float w0 = (s * s * s) * (1.0f / 6.0f);
  float w3 = t3 * (1.0f / 6.0f);
  float w1 = fmaf(0.5f, t3, 2.0f / 3.0f) - t2;
  float w2 = 1.0f - w0 - w1 - w3;
  int ls = mi - 3;                       // 0..7
  ull W64 = (ull)f2bf(w0)
          | ((ull)f2bf(w1) << 16)
          | ((ull)f2bf(w2) << 32)
          | ((ull)f2bf(w3) << 48);
  int sh = ls << 4;                      // 0..112
  int a  = sh & 63;
  ull lop  = W64 << a;
  ull hip_ = a ? (W64 >> (64 - a)) : 0ull;
  W[0] = (sh < 64) ? lop : 0ull;
  W[1] = (sh < 64) ? hip_ : lop;
  W[2] = ((sh < 64) ? 0ull : hip_) | ((ull)f2bf(xx) << 48); // slot 11 = x
}

// ---- kernel 1T: weights -> tiled WtT[bn][kt][gran12][col128][8] bf16 --------
__global__ __launch_bounds__(256) void kan_build_wtT(
    const float* __restrict__ sw,        // [OUTF][INF][11]
    const float* __restrict__ bw,        // [OUTF][INF]
    us* __restrict__ WtT)
{
  int t   = blockIdx.x * 256 + threadIdx.x;   // 0..524287
  int col = t & 127;
  int q   = t >> 7;
  int f0  = (q & 3) * 2;                      // 0,2,4,6
  int kt  = (q >> 2) & 127;
  int bn  = q >> 9;
  int o   = bn * 128 + col;
  int i0  = kt * 8 + f0;

  us v[24];
#pragma unroll
  for (int j = 0; j < 2; ++j) {
    int i = i0 + j;
    const float* s = sw + (size_t)(o * 1024 + i) * 11;
#pragma unroll
    for (int l = 0; l < 11; ++l) v[j * 12 + l] = f2bf(s[l]);
    v[j * 12 + 11] = f2bf(bw[o * 1024 + i]);
  }
  int g0 = (f0 >> 1) * 3;
  U2* p = reinterpret_cast<U2*>(WtT + (size_t)(bn * 128 + kt) * 12 * 1024);
#pragma unroll
  for (int j = 0; j < 3; ++j) {
    U2 u;
    const us* w = v + j * 8;
    u.x = (ull)w[0] | ((ull)w[1] << 16) | ((ull)w[2] << 32) | ((ull)w[3] << 48);
    u.y = (ull)w[4] | ((ull)w[5] << 16) | ((ull)w[6] << 32) | ((ull)w[7] << 48);
    p[(g0 + j) * 128 + col] = u;
  }
}

// ---- kernel 2: basis prepass -> At[bm][kt][gran12][row256][8] bf16 ----------
__global__ __launch_bounds__(1024) void kan_build_at(
    const float* __restrict__ x,         // [BATCH][INF]
    us* __restrict__ At)
{
  int b  = blockIdx.x;                   // 0..2047
  int bm = b >> 7;
  int kt = b & 127;
  int r  = threadIdx.x & 255;
  int f0 = (threadIdx.x >> 8) * 2;       // 0,2,4,6

  float2 xv = *reinterpret_cast<const float2*>(
      x + (size_t)(bm * 256 + r) * INF + kt * 8 + f0);

  ull W[6];
  basis12(xv.x, W + 0);
  basis12(xv.y, W + 3);

  int g0 = (f0 >> 1) * 3;
  U2* p = reinterpret_cast<U2*>(At + (size_t)(bm * 128 + kt) * 12 * 2048);
  U2 u0; u0.x = W[0]; u0.y = W[1];
  U2 u1; u1.x = W[2]; u1.y = W[3];
  U2 u2; u2.x = W[4]; u2.y = W[5];
  p[(g0 + 0) * 256 + r] = u0;            // lane-consecutive 16B -> coalesced
  p[(g0 + 1) * 256 + r] = u1;
  p[(g0 + 2) * 256 + r] = u2;
}

// ---- kernel 3: pure GEMM, 256x128 tile, k-split x2, 3-phase counted-vmcnt ---
__global__ __launch_bounds__(THREADS, 1) void kan_gemm(
    const us* __restrict__ At,           // tiled A
    const us* __restrict__ WtT,          // tiled B
    float* __restrict__ out)             // [BATCH][OUTF], pre-zeroed
{
  __shared__ alignas(16) us smem[2 * ASZ + 2 * BSZ];   // 147456 B

  const int tid  = threadIdx.x;
  const int lane = tid & 63;
  const int wid  = tid >> 6;              // 0..7
  const int wm   = (wid >> 1) * 64;       // 4 wave-rows of 64
  const int wn   = (wid & 1) * 64;        // 2 wave-cols of 64
  const int lr   = lane & 15;
  const int lk   = lane >> 4;
  const int b    = (int)blockIdx.x;       // 0..255
  const int bn   = b & 7;                 // XCD-local Wt panel
  const int kh   = (b >> 3) & 1;
  const int bm   = b >> 4;                // 0..15

  us* Acur = smem;
  us* Aalt = smem + ASZ;
  us* Bcur = smem + 2 * ASZ;
  us* Balt = smem + 2 * ASZ + BSZ;

  f32x4 acc[4][4] = {};

  // issue this wave's 3 DMA slots for phase p of K-tile ktG into (Ad,Bd)
  auto issue3 = [&](int ktG, us* Ad, us* Bd, int p) {
#pragma unroll
    for (int j = 0; j < 3; ++j) {
      int s = wid * 3 + j;                // 0..23
      if (s < 16) {                       // A: 4 granules x 4 KB = 16 x 1KB
        int g = p * 4 + (s >> 2), h = s & 3;
        const us* src = At + ((size_t)(bm * 128 + ktG) * 12 + g) * 2048
                           + h * 512 + lane * 8;
        async_copy16(src, Ad + g * 2048 + h * 512);
      } else {                            // B: 4 granules x 2 KB = 8 x 1KB
        int sb = s - 16;
        int g = p * 4 + (sb >> 1), h = sb & 1;
        const us* src = WtT + ((size_t)(bn * 128 + ktG) * 12 + g) * 1024
                            + h * 512 + lane * 8;
        async_copy16(src, Bd + g * 1024 + h * 512);
      }
    }
  };

  bf16x8 af[4], bfr[4];
  auto readFrags = [&](int p) {
    const int g = p * 4 + lk;             // granule 0..11
#pragma unroll
    for (int mf = 0; mf < 4; ++mf)
      af[mf] = *reinterpret_cast<const bf16x8*>(
          &Acur[(g * 256 + wm + mf * 16 + lr) * 8]);
#pragma unroll
    for (int nf = 0; nf < 4; ++nf)
      bfr[nf] = *reinterpret_cast<const bf16x8*>(
          &Bcur[(g * 128 + wn + nf * 16 + lr) * 8]);
  };
  auto doMFMA = [&]() {
    __builtin_amdgcn_s_setprio(1);
#pragma unroll
    for (int mf = 0; mf < 4; ++mf)
#pragma unroll
      for (int nf = 0; nf < 4; ++nf)
        acc[mf][nf] = __builtin_amdgcn_mfma_f32_16x16x32_bf16(
            af[mf], bfr[nf], acc[mf][nf], 0, 0, 0);
    __builtin_amdgcn_s_setprio(0);
  };

  // ---- prologue: stage K-tile 0 (9 DMAs/wave, in phase order) ----
  const int kt0 = kh * 64;
#pragma unroll
  for (int p = 0; p < 3; ++p) issue3(kt0, Acur, Bcur, p);

  for (int c = 0; c < 64; ++c) {
    const int cn   = (c + 1 < 64) ? (c + 1) : 63;   // clamped (dup unread)
    const int ktGn = kh * 64 + cn;
#pragma unroll
    for (int p = 0; p < 3; ++p) {
      WAIT_VM(6);               // own 3 DMAs of set (c,p) drained
      BARRIER();                // everyone's set-(c,p) DMAs visible
      issue3(ktGn, Aalt, Balt, p);   // prefetch next tile's set p
      readFrags(p);
      WAIT_LGKM0();
      doMFMA();                 // 16 MFMA, k32
    }
    us* t = Acur; Acur = Aalt; Aalt = t;
    t = Bcur; Bcur = Balt; Balt = t;
  }

  asm volatile("s_waitcnt vmcnt(0) lgkmcnt(0)" ::: "memory");

  // ---- epilogue: atomic merge of the two k-halves (2 addends: deterministic)
#pragma unroll
  for (int mf = 0; mf < 4; ++mf) {
#pragma unroll
    for (int v = 0; v < 4; ++v) {
      int row = bm * BM + wm + mf * 16 + lk * 4 + v;
      float* orow = out + (size_t)row * OUTF + bn * BN + wn + lr;
#pragma unroll
      for (int nf = 0; nf < 4; ++nf)
        atomicAdd(&orow[nf * 16], acc[mf][nf][v]);
    }
  }
}

// ======================= fallback path (R8, proven 168 us) ===================
#define FB_IC 4
#define FB_BK 48
#define FB_NCHUNK 128
#define FB_BUFSZ (6*128*8)

__global__ __launch_bounds__(256) void kan_build_wt(
    const float* __restrict__ sw, const float* __restrict__ bw,
    us* __restrict__ Wt)
{
  int idx = blockIdx.x * 256 + threadIdx.x;
  int o = idx >> 10;
  int i = idx & 1023;
  const float* s = sw + (size_t)(o * 1024 + i) * 11;
  us v[12];
#pragma unroll
  for (int l = 0; l < 11; ++l) v[l] = f2bf(s[l]);
  v[11] = f2bf(bw[o * 1024 + i]);
  us* d = Wt + (size_t)o * KTOT + i * 12;
  *reinterpret_cast<ushort4*>(d + 0) = make_ushort4(v[0], v[1], v[2],  v[3]);
  *reinterpret_cast<ushort4*>(d + 4) = make_ushort4(v[4], v[5], v[6],  v[7]);
  *reinterpret_cast<ushort4*>(d + 8) = make_ushort4(v[8], v[9], v[10], v[11]);
}

__global__ __launch_bounds__(512, 4) void kan_gemm_fb(
    const float* __restrict__ x, const us* __restrict__ Wt,
    float* __restrict__ out)
{
  __shared__ alignas(16) us smem[5 * FB_BUFSZ];
  const int tid  = threadIdx.x;
  const int lane = tid & 63;
  const int wid  = tid >> 6;
  const int wm   = (wid >> 2) * 64;
  const int wn   = (wid & 3) * 32;
  const int lo   = lane & 31;
  const int lh   = lane >> 5;
  const int idx  = (int)blockIdx.x;
  const int bn   = idx & 7;
  const int kh   = (idx >> 3) & 1;
  const int bm   = idx >> 4;
  const bool builder = (tid < 256);
  const bool stager  = (wid >= 4);
  const int ab  = tid & 127;
  const int ai0 = ((tid >> 7) & 1) << 1;
  const float* xrow = x + (size_t)(bm * 128 + ab) * INF + kh * 512 + ai0;
  const size_t kbase = (size_t)kh * (KTOT / 2);

  us* Bcur = smem;            us* Bnxt = smem + FB_BUFSZ;
  us* Bnn  = smem + 2 * FB_BUFSZ;
  us* Acur = smem + 3 * FB_BUFSZ; us* Aalt = smem + 4 * FB_BUFSZ;
  f32x16 acc[2] = {};

  auto stageB = [&](int c, us* Bd) {
    const int wq = wid - 4;
#pragma unroll
    for (int qq = 0; qq < 3; ++qq) {
      int G  = (wq * 3 + qq) * 64 + lane;
      int kk = G >> 7;
      int oo = G & 127;
      const us* src = Wt + (size_t)(bn * 128 + oo) * KTOT + kbase + c * FB_BK + kk * 8;
      async_copy16(src, Bd + (wq * 3 + qq) * 512);
    }
  };
  auto buildA = [&](float2 xv, us* Ad) {
    ull W[6];
    basis12(xv.x, W + 0);
    basis12(xv.y, W + 3);
    U2* p = reinterpret_cast<U2*>(Ad);
    const int g0 = (ai0 >> 1) * 3;
    U2 u0; u0.x = W[0]; u0.y = W[1];
    U2 u1; u1.x = W[2]; u1.y = W[3];
    U2 u2; u2.x = W[4]; u2.y = W[5];
    p[(g0 + 0) * 128 + ab] = u0;
    p[(g0 + 1) * 128 + ab] = u1;
    p[(g0 + 2) * 128 + ab] = u2;
  };

  float2 xa = make_float2(0.f, 0.f);
  if (builder) {
    float2 x0v = *reinterpret_cast<const float2*>(xrow);
    buildA(x0v, Acur);
    xa = *reinterpret_cast<const float2*>(xrow + FB_IC);
  }
  if (stager) { stageB(0, Bcur); stageB(1, Bnxt); }
  WAIT_VM(3); BARRIER();

  for (int c = 0; c < FB_NCHUNK; ++c) {
    int cf = (c + 2 < FB_NCHUNK) ? (c + 2) : (FB_NCHUNK - 1);
    float2 xb = xa;
    if (builder) {
      xb = *reinterpret_cast<const float2*>(xrow + cf * FB_IC);
      buildA(xa, Aalt);
    }
    if (stager) stageB(cf, Bnn);
#pragma unroll
    for (int s = 0; s < 3; ++s) {
      const int kk = s * 2 + lh;
      bf16x8 a0 = *reinterpret_cast<const bf16x8*>(&Acur[(kk * 128 + wm + lo) * 8]);
      bf16x8 a1 = *reinterpret_cast<const bf16x8*>(&Acur[(kk * 128 + wm + 32 + lo) * 8]);
      bf16x8 b0 = *reinterpret_cast<const bf16x8*>(&Bcur[(kk * 128 + wn + lo) * 8]);
      acc[0] = __builtin_amdgcn_mfma_f32_32x32x16_bf16(a0, b0, acc[0], 0, 0, 0);
      acc[1] = __builtin_amdgcn_mfma_f32_32x32x16_bf16(a1, b0, acc[1], 0, 0, 0);
    }
    WAIT_VM(3); BARRIER();
    us* t = Bcur; Bcur = Bnxt; Bnxt = Bnn; Bnn = t;
    t = Acur; Acur = Aalt; Aalt = t;
    xa = xb;
  }
  asm volatile("s_waitcnt vmcnt(0) lgkmcnt(0)" ::: "memory");
#pragma unroll
  for (int mf = 0; mf < 2; ++mf)
#pragma unroll
    for (int r = 0; r < 16; ++r) {
      int row = bm * 128 + wm + mf * 32 + (r & 3) + 8 * (r >> 2) + 4 * lh;
      atomicAdd(out + (size_t)row * OUTF + bn * 128 + wn + lo, acc[mf][r]);
    }
}

// =============================================================================
extern "C" void kernel_launch(void* const* d_in, const int* in_sizes, int n_in,
                              void* d_out, int out_size, void* d_ws, size_t ws_size,
                              hipStream_t stream) {
  const float* x  = (const float*)d_in[0];   // [4096][1024]
  const float* bw = (const float*)d_in[1];   // [1024][1024]
  const float* sw = (const float*)d_in[2];   // [1024][1024][11]
  float* out = (float*)d_out;

  if (ws_size >= WTT_BYTES + AT_BYTES) {
    us* WtT = (us*)d_ws;
    us* At  = (us*)((char*)d_ws + WTT_BYTES);
    kan_build_wtT<<<2048, 256, 0, stream>>>(sw, bw, WtT);
    kan_build_at<<<2048, 1024, 0, stream>>>(x, At);
    hipMemsetAsync(d_out, 0, OUT_BYTES, stream);
    kan_gemm<<<256, THREADS, 0, stream>>>(At, WtT, out);
  } else if (ws_size >= WTT_BYTES) {
    us* Wt = (us*)d_ws;
    kan_build_wt<<<(OUTF * INF) / 256, 256, 0, stream>>>(sw, bw, Wt);
    hipMemsetAsync(d_out, 0, OUT_BYTES, stream);
    kan_gemm_fb<<<512, 512, 0, stream>>>(x, Wt, out);
  }
}

// Round 11
// 164.201 us; speedup vs baseline: 1.1716x; 1.1716x over previous
//
#include <hip/hip_runtime.h>
#include <hip/hip_bf16.h>
#include <cstdint>

#define BATCH 4096
#define INF   1024
#define OUTF  1024
#define LCH   12
#define KTOT  (INF*LCH)       // 12288
#define BM    256
#define BN    256
#define BK    48              // 4 features per K-tile
#define NT    64              // K-tiles per k-quarter (256 features / 4)
#define THREADS 512
#define TSZ   (6*256*8)       // 12288 us = 24 KB per tile buffer (A or B)

#define WTT_BYTES ((size_t)OUTF * KTOT * 2)            // 25165824
#define PART_FLOATS ((size_t)BATCH * OUTF)             // 4194304
#define OUT_BYTES (PART_FLOATS * 4)                    // 16777216

typedef __bf16 bf16x8 __attribute__((ext_vector_type(8)));
typedef float  f32x16 __attribute__((ext_vector_type(16)));
typedef unsigned long long ull;
typedef unsigned short us;

struct alignas(16) U2 { ull x, y; };

__device__ __forceinline__ us f2bf(float f) {
  unsigned int u = __builtin_bit_cast(unsigned int, f);
  u += 0x7FFFu + ((u >> 16) & 1u);
  return (us)(u >> 16);
}

__device__ __forceinline__ void async_copy16(const void* g, void* l) {
  __builtin_amdgcn_global_load_lds(
      (const __attribute__((address_space(1))) unsigned int*)g,
      (__attribute__((address_space(3))) unsigned int*)l,
      16, 0, 0);
}

// keep the newest 4 VMEM ops (this iter's x-load + 3 B-DMAs) in flight;
// drain everything older + all LDS ops, then block barrier.
#define PIPE_BARRIER() do {                                        \
  asm volatile("s_waitcnt vmcnt(4) lgkmcnt(0)" ::: "memory");      \
  __builtin_amdgcn_sched_barrier(0);                               \
  __builtin_amdgcn_s_barrier();                                    \
  __builtin_amdgcn_sched_barrier(0);                               \
} while (0)

// 12 bf16 channels (11 spline + base/x) for one feature value
__device__ __forceinline__ void basis12(float xx, ull W[3]) {
  float u  = fmaf(xx, 4.0f, 7.0f);       // in (3,11); x in (-1,1)
  float fm = floorf(u);
  int   mi = (int)fm;                    // 3..10
  float t  = u - fm;
  float s  = 1.0f - t;
  float t2 = t * t, t3 = t2 * t;
  float w0 = (s * s * s) * (1.0f / 6.0f);
  float w3 = t3 * (1.0f / 6.0f);
  float w1 = fmaf(0.5f, t3, 2.0f / 3.0f) - t2;
  float w2 = 1.0f - w0 - w1 - w3;
  int ls = mi - 3;                       // 0..7
  ull W64 = (ull)f2bf(w0)
          | ((ull)f2bf(w1) << 16)
          | ((ull)f2bf(w2) << 32)
          | ((ull)f2bf(w3) << 48);
  int sh = ls << 4;                      // 0..112
  int a  = sh & 63;
  ull lop  = W64 << a;
  ull hip_ = a ? (W64 >> (64 - a)) : 0ull;
  W[0] = (sh < 64) ? lop : 0ull;
  W[1] = (sh < 64) ? hip_ : lop;
  W[2] = ((sh < 64) ? 0ull : hip_) | ((ull)f2bf(xx) << 48); // slot 11 = x
}

// ---- kernel 1: weights -> tiled WtT[bn4][ktG256][gran6][col256][8] bf16 -----
__global__ __launch_bounds__(256) void kan_build_wtT(
    const float* __restrict__ sw,        // [OUTF][INF][11]
    const float* __restrict__ bw,        // [OUTF][INF]
    us* __restrict__ WtT)
{
  int t   = blockIdx.x * 256 + threadIdx.x;   // 0..524287
  int col = t & 255;
  int q   = t >> 8;                           // 0..2047
  int fp  = q & 1;                            // feature pair in tile
  int ktG = (q >> 1) & 255;                   // global K-tile (4 feats)
  int bn  = q >> 9;                           // 0..3
  int o   = bn * 256 + col;
  int i0  = ktG * 4 + fp * 2;

  us v[24];
#pragma unroll
  for (int j = 0; j < 2; ++j) {
    int i = i0 + j;
    const float* s = sw + (size_t)(o * 1024 + i) * 11;
#pragma unroll
    for (int l = 0; l < 11; ++l) v[j * 12 + l] = f2bf(s[l]);
    v[j * 12 + 11] = f2bf(bw[o * 1024 + i]);
  }
  int g0 = fp * 3;
  us* base = WtT + (size_t)(bn * 256 + ktG) * (6 * 256 * 8);
  U2* p = reinterpret_cast<U2*>(base);
#pragma unroll
  for (int j = 0; j < 3; ++j) {
    U2 u;
    const us* w = v + j * 8;
    u.x = (ull)w[0] | ((ull)w[1] << 16) | ((ull)w[2] << 32) | ((ull)w[3] << 48);
    u.y = (ull)w[4] | ((ull)w[5] << 16) | ((ull)w[6] << 32) | ((ull)w[7] << 48);
    p[(g0 + j) * 256 + col] = u;
  }
}

// ---- kernel 2: fused GEMM, 256x256 tile, k-quarter split, 128x64 waves ------
__global__ __launch_bounds__(THREADS, 2) void kan_gemm(
    const float* __restrict__ x,             // [BATCH][INF]
    const us* __restrict__ WtT,              // tiled B
    float* __restrict__ P)                   // partials [4][BATCH][OUTF]
{
  // A dbuf (2) + B tribuf (3), each [gran6][256][8] = 24 KB -> 120 KB
  __shared__ alignas(16) us smem[5 * TSZ];

  const int tid  = threadIdx.x;
  const int lane = tid & 63;
  const int wid  = tid >> 6;              // 0..7
  const int wm   = (wid >> 2) * 128;      // 2 row groups of 128
  const int wn   = (wid & 3) * 64;        // 4 col groups of 64
  const int lo   = lane & 31;
  const int lh   = lane >> 5;
  const int b    = (int)blockIdx.x;       // 0..255
  const int bn   = b & 3;
  const int kq   = (b >> 2) & 3;          // k-quarter
  const int bm   = b >> 4;                // 0..15

  // A-build mapping: thread -> (row r, feature pair fp)
  const int r   = tid & 255;
  const int fp  = tid >> 8;               // 0 or 1
  const int g0A = fp * 3;
  const float* xrow = x + (size_t)(bm * BM + r) * INF + kq * 256 + fp * 2;

  us* Acur = smem;
  us* Aalt = smem + TSZ;
  us* Bcur = smem + 2 * TSZ;
  us* Bnxt = smem + 3 * TSZ;
  us* Bnn  = smem + 4 * TSZ;

  f32x16 acc[4][2] = {};

  auto stageB = [&](int c, us* Bd) {
    const int ktG = kq * NT + c;
    const us* base = WtT + (size_t)(bn * 256 + ktG) * (6 * 256 * 8);
#pragma unroll
    for (int j = 0; j < 3; ++j) {
      int s = wid * 3 + j;                // chunk 0..23 (1 KB each)
      int g = s >> 2, h = s & 3;
      async_copy16(base + g * 2048 + h * 512 + lane * 8,
                   Bd + g * 2048 + h * 512);   // wave-uniform dest; HW adds lane*16
    }
  };

  auto buildA = [&](float2 xv, us* Ad) {
    ull W[6];
    basis12(xv.x, W + 0);
    basis12(xv.y, W + 3);
    U2* p = reinterpret_cast<U2*>(Ad);
    U2 u0; u0.x = W[0]; u0.y = W[1];
    U2 u1; u1.x = W[2]; u1.y = W[3];
    U2 u2; u2.x = W[4]; u2.y = W[5];
    p[(g0A + 0) * 256 + r] = u0;          // lane-consecutive 16B -> conflict-free
    p[(g0A + 1) * 256 + r] = u1;
    p[(g0A + 2) * 256 + r] = u2;
  };

  // ---- prologue ----
  {
    float2 x0 = *reinterpret_cast<const float2*>(xrow);   // K-tile 0 feats
    buildA(x0, Acur);
    stageB(0, Bcur);                                      // 3 DMA
    stageB(1, Bnxt);                                      // 3 DMA
  }
  float2 xa = *reinterpret_cast<const float2*>(xrow + 4); // K-tile 1 feats
  PIPE_BARRIER();   // drains B0 + A0 writes; keeps {B1 DMAs, xa} in flight

  for (int c = 0; c < NT; ++c) {
    const int cf = (c + 2 < NT) ? (c + 2) : (NT - 1);
    float2 xb = *reinterpret_cast<const float2*>(xrow + cf * 4);   // vmem #1
    stageB(cf, Bnn);                                               // vmem #2-4
    buildA(xa, Aalt);          // K-tile c+1 basis (VALU + 3 ds_write)

    // ---- MFMA: 3 k-steps of 16 (32x32x16), 24 MFMA ----
#pragma unroll
    for (int s = 0; s < 3; ++s) {
      const int kk = s * 2 + lh;            // granule 0..5
      bf16x8 af[4], bf[2];
#pragma unroll
      for (int f = 0; f < 4; ++f)
        af[f] = *reinterpret_cast<const bf16x8*>(
            &Acur[(kk * 256 + wm + f * 32 + lo) * 8]);
#pragma unroll
      for (int n = 0; n < 2; ++n)
        bf[n] = *reinterpret_cast<const bf16x8*>(
            &Bcur[(kk * 256 + wn + n * 32 + lo) * 8]);
#pragma unroll
      for (int f = 0; f < 4; ++f)
#pragma unroll
        for (int n = 0; n < 2; ++n)
          acc[f][n] = __builtin_amdgcn_mfma_f32_32x32x16_bf16(
              af[f], bf[n], acc[f][n], 0, 0, 0);
    }

    PIPE_BARRIER();

    us* t = Bcur; Bcur = Bnxt; Bnxt = Bnn; Bnn = t;
    t = Acur; Acur = Aalt; Aalt = t;
    xa = xb;
  }

  asm volatile("s_waitcnt vmcnt(0) lgkmcnt(0)" ::: "memory");

  // ---- epilogue: C/D row=(r&3)+8*(r>>2)+4*lh, col=lo (verified R4/R7/R8) ----
  float* dst = P + (size_t)kq * PART_FLOATS;
#pragma unroll
  for (int f = 0; f < 4; ++f) {
#pragma unroll
    for (int rr = 0; rr < 16; ++rr) {
      int row = bm * BM + wm + f * 32 + (rr & 3) + 8 * (rr >> 2) + 4 * lh;
      float* orow = dst + (size_t)row * OUTF + bn * BN + wn + lo;
#pragma unroll
      for (int n = 0; n < 2; ++n)
        orow[n * 32] = acc[f][n][rr];
    }
  }
}

// ---- kernel 3: out = (p0+p1)+(p2+p3), fixed order -> deterministic ----------
__global__ __launch_bounds__(256) void kan_reduce4(
    float4* __restrict__ out, const float4* __restrict__ p)
{
  size_t i = (size_t)blockIdx.x * 256 + threadIdx.x;   // 0..1048575
  const size_t Q = PART_FLOATS / 4;
  float4 a = p[i], bq = p[i + Q], c = p[i + 2 * Q], d = p[i + 3 * Q];
  float4 o;
  o.x = (a.x + bq.x) + (c.x + d.x);
  o.y = (a.y + bq.y) + (c.y + d.y);
  o.z = (a.z + bq.z) + (c.z + d.z);
  o.w = (a.w + bq.w) + (c.w + d.w);
  out[i] = o;
}

// ======================= fallback path (R8-class, proven) ====================
#define FB_BUFSZ (6*128*8)

__global__ __launch_bounds__(256) void kan_build_wt(
    const float* __restrict__ sw, const float* __restrict__ bw,
    us* __restrict__ Wt)
{
  int idx = blockIdx.x * 256 + threadIdx.x;
  int o = idx >> 10;
  int i = idx & 1023;
  const float* s = sw + (size_t)(o * 1024 + i) * 11;
  us v[12];
#pragma unroll
  for (int l = 0; l < 11; ++l) v[l] = f2bf(s[l]);
  v[11] = f2bf(bw[o * 1024 + i]);
  us* d = Wt + (size_t)o * KTOT + i * 12;
  *reinterpret_cast<ushort4*>(d + 0) = make_ushort4(v[0], v[1], v[2],  v[3]);
  *reinterpret_cast<ushort4*>(d + 4) = make_ushort4(v[4], v[5], v[6],  v[7]);
  *reinterpret_cast<ushort4*>(d + 8) = make_ushort4(v[8], v[9], v[10], v[11]);
}

__global__ __launch_bounds__(512, 4) void kan_gemm_fb(
    const float* __restrict__ x, const us* __restrict__ Wt,
    float* __restrict__ out)
{
  __shared__ alignas(16) us smem[5 * FB_BUFSZ];
  const int tid  = threadIdx.x;
  const int lane = tid & 63;
  const int wid  = tid >> 6;
  const int wm   = (wid >> 2) * 64;
  const int wn   = (wid & 3) * 32;
  const int lo   = lane & 31;
  const int lh   = lane >> 5;
  const int idx  = (int)blockIdx.x;
  const int bn   = idx & 7;
  const int kh   = (idx >> 3) & 1;
  const int bm   = idx >> 4;
  const bool builder = (tid < 256);
  const bool stager  = (wid >= 4);
  const int ab  = tid & 127;
  const int ai0 = ((tid >> 7) & 1) << 1;
  const float* xrow = x + (size_t)(bm * 128 + ab) * INF + kh * 512 + ai0;
  const size_t kbase = (size_t)kh * (KTOT / 2);

  us* Bcur = smem;            us* Bnxt = smem + FB_BUFSZ;
  us* Bnn  = smem + 2 * FB_BUFSZ;
  us* Acur = smem + 3 * FB_BUFSZ; us* Aalt = smem + 4 * FB_BUFSZ;
  f32x16 acc[2] = {};

  auto stageB = [&](int c, us* Bd) {
    const int wq = wid - 4;
#pragma unroll
    for (int qq = 0; qq < 3; ++qq) {
      int G  = (wq * 3 + qq) * 64 + lane;
      int kk = G >> 7;
      int oo = G & 127;
      const us* src = Wt + (size_t)(bn * 128 + oo) * KTOT + kbase + c * 48 + kk * 8;
      async_copy16(src, Bd + (wq * 3 + qq) * 512);
    }
  };
  auto buildA = [&](float2 xv, us* Ad) {
    ull W[6];
    basis12(xv.x, W + 0);
    basis12(xv.y, W + 3);
    U2* p = reinterpret_cast<U2*>(Ad);
    const int g0 = (ai0 >> 1) * 3;
    U2 u0; u0.x = W[0]; u0.y = W[1];
    U2 u1; u1.x = W[2]; u1.y = W[3];
    U2 u2; u2.x = W[4]; u2.y = W[5];
    p[(g0 + 0) * 128 + ab] = u0;
    p[(g0 + 1) * 128 + ab] = u1;
    p[(g0 + 2) * 128 + ab] = u2;
  };

  float2 xa = make_float2(0.f, 0.f);
  if (builder) {
    float2 x0v = *reinterpret_cast<const float2*>(xrow);
    buildA(x0v, Acur);
    xa = *reinterpret_cast<const float2*>(xrow + 4);
  }
  if (stager) { stageB(0, Bcur); stageB(1, Bnxt); }
  asm volatile("s_waitcnt vmcnt(3) lgkmcnt(0)" ::: "memory");
  __builtin_amdgcn_s_barrier();

  for (int c = 0; c < 128; ++c) {
    int cf = (c + 2 < 128) ? (c + 2) : 127;
    float2 xb = xa;
    if (builder) {
      xb = *reinterpret_cast<const float2*>(xrow + cf * 4);
      buildA(xa, Aalt);
    }
    if (stager) stageB(cf, Bnn);
#pragma unroll
    for (int s = 0; s < 3; ++s) {
      const int kk = s * 2 + lh;
      bf16x8 a0 = *reinterpret_cast<const bf16x8*>(&Acur[(kk * 128 + wm + lo) * 8]);
      bf16x8 a1 = *reinterpret_cast<const bf16x8*>(&Acur[(kk * 128 + wm + 32 + lo) * 8]);
      bf16x8 b0 = *reinterpret_cast<const bf16x8*>(&Bcur[(kk * 128 + wn + lo) * 8]);
      acc[0] = __builtin_amdgcn_mfma_f32_32x32x16_bf16(a0, b0, acc[0], 0, 0, 0);
      acc[1] = __builtin_amdgcn_mfma_f32_32x32x16_bf16(a1, b0, acc[1], 0, 0, 0);
    }
    asm volatile("s_waitcnt vmcnt(3) lgkmcnt(0)" ::: "memory");
    __builtin_amdgcn_s_barrier();
    us* t = Bcur; Bcur = Bnxt; Bnxt = Bnn; Bnn = t;
    t = Acur; Acur = Aalt; Aalt = t;
    xa = xb;
  }
  asm volatile("s_waitcnt vmcnt(0) lgkmcnt(0)" ::: "memory");
#pragma unroll
  for (int mf = 0; mf < 2; ++mf)
#pragma unroll
    for (int r2 = 0; r2 < 16; ++r2) {
      int row = bm * 128 + wm + mf * 32 + (r2 & 3) + 8 * (r2 >> 2) + 4 * lh;
      atomicAdd(out + (size_t)row * OUTF + bn * 128 + wn + lo, acc[mf][r2]);
    }
}

// =============================================================================
extern "C" void kernel_launch(void* const* d_in, const int* in_sizes, int n_in,
                              void* d_out, int out_size, void* d_ws, size_t ws_size,
                              hipStream_t stream) {
  const float* x  = (const float*)d_in[0];   // [4096][1024]
  const float* bw = (const float*)d_in[1];   // [1024][1024]
  const float* sw = (const float*)d_in[2];   // [1024][1024][11]
  float* out = (float*)d_out;

  if (ws_size >= WTT_BYTES + 4 * OUT_BYTES) {
    us* WtT  = (us*)d_ws;
    float* P = (float*)((char*)d_ws + WTT_BYTES);
    kan_build_wtT<<<2048, 256, 0, stream>>>(sw, bw, WtT);
    kan_gemm<<<256, THREADS, 0, stream>>>(x, WtT, P);
    kan_reduce4<<<(int)(PART_FLOATS / 4 / 256), 256, 0, stream>>>(
        (float4*)out, (const float4*)P);
  } else if (ws_size >= WTT_BYTES) {
    us* Wt = (us*)d_ws;
    kan_build_wt<<<(OUTF * INF) / 256, 256, 0, stream>>>(sw, bw, Wt);
    hipMemsetAsync(d_out, 0, OUT_BYTES, stream);
    kan_gemm_fb<<<512, 512, 0, stream>>>(x, Wt, out);
  }
}

// Round 13
// 160.762 us; speedup vs baseline: 1.1966x; 1.0214x over previous
//
#include <hip/hip_runtime.h>
#include <hip/hip_bf16.h>
#include <cstdint>

#define BATCH 4096
#define INF   1024
#define OUTF  1024
#define LCH   12
#define KTOT  (INF*LCH)       // 12288
#define BM    256
#define BN    256
#define BK    48              // 4 features per K-tile
#define NT    64              // K-tiles per k-quarter
#define THREADS 512
#define TSZ   (6*256*8)       // 12288 us = 24 KB per tile buffer (A or B)

#define WTT_BYTES ((size_t)OUTF * KTOT * 2)            // 25165824
#define PART_FLOATS ((size_t)BATCH * OUTF)             // 4194304
#define OUT_BYTES (PART_FLOATS * 4)                    // 16777216

typedef __bf16 bf16x8 __attribute__((ext_vector_type(8)));
typedef float  f32x16 __attribute__((ext_vector_type(16)));
typedef unsigned long long ull;
typedef unsigned short us;

struct alignas(16) U2 { ull x, y; };

__device__ __forceinline__ us f2bf(float f) {
  unsigned int u = __builtin_bit_cast(unsigned int, f);
  u += 0x7FFFu + ((u >> 16) & 1u);
  return (us)(u >> 16);
}

__device__ __forceinline__ void async_copy16(const void* g, void* l) {
  __builtin_amdgcn_global_load_lds(
      (const __attribute__((address_space(1))) unsigned int*)g,
      (__attribute__((address_space(3))) unsigned int*)l,
      16, 0, 0);
}

// keep the newest 4 VMEM ops (this iter's x-load + 3 B-DMAs) in flight;
// drain everything older + all LDS ops, then block barrier.
// INVARIANT: exactly 4 intended VMEM ops per iteration, no compiler-generated
// VMEM (no scratch spills) — keep all loop state in named scalars.
#define PIPE_BARRIER() do {                                        \
  asm volatile("s_waitcnt vmcnt(4) lgkmcnt(0)" ::: "memory");      \
  __builtin_amdgcn_sched_barrier(0);                               \
  __builtin_amdgcn_s_barrier();                                    \
  __builtin_amdgcn_sched_barrier(0);                               \
} while (0)

// 12 bf16 channels (11 spline + base/x) for one feature value (scalar path)
__device__ __forceinline__ void basis12(float xx, ull W[3]) {
  float u  = fmaf(xx, 4.0f, 7.0f);       // in (3,11); x in (-1,1)
  float fm = floorf(u);
  int   mi = (int)fm;                    // 3..10
  float t  = u - fm;
  float s  = 1.0f - t;
  float t2 = t * t, t3 = t2 * t;
  float w0 = (s * s * s) * (1.0f / 6.0f);
  float w3 = t3 * (1.0f / 6.0f);
  float w1 = fmaf(0.5f, t3, 2.0f / 3.0f) - t2;
  float w2 = 1.0f - w0 - w1 - w3;
  int ls = mi - 3;                       // 0..7
  ull W64 = (ull)f2bf(w0)
          | ((ull)f2bf(w1) << 16)
          | ((ull)f2bf(w2) << 32)
          | ((ull)f2bf(w3) << 48);
  int sh = ls << 4;                      // 0..112
  int a  = sh & 63;
  ull lop  = W64 << a;
  ull hip_ = a ? (W64 >> (64 - a)) : 0ull;
  W[0] = (sh < 64) ? lop : 0ull;
  W[1] = (sh < 64) ? hip_ : lop;
  W[2] = ((sh < 64) ? 0ull : hip_) | ((ull)f2bf(xx) << 48); // slot 11 = x
}

// ---- kernel 1: weights -> tiled WtT[bn4][ktG256][gran6][col256][8] bf16 -----
__global__ __launch_bounds__(256) void kan_build_wtT(
    const float* __restrict__ sw,        // [OUTF][INF][11]
    const float* __restrict__ bw,        // [OUTF][INF]
    us* __restrict__ WtT)
{
  int t   = blockIdx.x * 256 + threadIdx.x;   // 0..524287
  int col = t & 255;
  int q   = t >> 8;                           // 0..2047
  int fp  = q & 1;                            // feature pair in tile
  int ktG = (q >> 1) & 255;                   // global K-tile (4 feats)
  int bn  = q >> 9;                           // 0..3
  int o   = bn * 256 + col;
  int i0  = ktG * 4 + fp * 2;

  us v[24];
#pragma unroll
  for (int j = 0; j < 2; ++j) {
    int i = i0 + j;
    const float* s = sw + (size_t)(o * 1024 + i) * 11;
#pragma unroll
    for (int l = 0; l < 11; ++l) v[j * 12 + l] = f2bf(s[l]);
    v[j * 12 + 11] = f2bf(bw[o * 1024 + i]);
  }
  int g0 = fp * 3;
  us* base = WtT + (size_t)(bn * 256 + ktG) * (6 * 256 * 8);
  U2* p = reinterpret_cast<U2*>(base);
#pragma unroll
  for (int j = 0; j < 3; ++j) {
    U2 u;
    const us* w = v + j * 8;
    u.x = (ull)w[0] | ((ull)w[1] << 16) | ((ull)w[2] << 32) | ((ull)w[3] << 48);
    u.y = (ull)w[4] | ((ull)w[5] << 16) | ((ull)w[6] << 32) | ((ull)w[7] << 48);
    p[(g0 + j) * 256 + col] = u;
  }
}

// basis for 2 features -> 6 named 64-bit words (all-static, cvt_pk packed)
#define BASIS2(XV, W0_,W1_,W2_,W3_,W4_,W5_) do {                         \
  {                                                                      \
    float xx = (XV).x;                                                   \
    float u_  = fmaf(xx, 4.0f, 7.0f);                                    \
    float fm_ = floorf(u_);                                              \
    int   mi_ = (int)fm_;                                                \
    float t_  = u_ - fm_;                                                \
    float s_  = 1.0f - t_;                                               \
    float t2_ = t_ * t_, t3_ = t2_ * t_;                                 \
    float w0_ = (s_ * s_ * s_) * (1.0f / 6.0f);                          \
    float w3_ = t3_ * (1.0f / 6.0f);                                     \
    float w1_ = fmaf(0.5f, t3_, 2.0f / 3.0f) - t2_;                      \
    float w2_ = 1.0f - w0_ - w1_ - w3_;                                  \
    unsigned int p01_, p23_;                                             \
    asm("v_cvt_pk_bf16_f32 %0, %1, %2" : "=v"(p01_) : "v"(w0_), "v"(w1_)); \
    asm("v_cvt_pk_bf16_f32 %0, %1, %2" : "=v"(p23_) : "v"(w2_), "v"(w3_)); \
    ull W64_ = (ull)p01_ | ((ull)p23_ << 32);                            \
    int sh_ = (mi_ - 3) << 4;                                            \
    int a_  = sh_ & 63;                                                  \
    ull lo_ = W64_ << a_;                                                \
    ull hi_ = a_ ? (W64_ >> (64 - a_)) : 0ull;                           \
    W0_ = (sh_ < 64) ? lo_ : 0ull;                                       \
    W1_ = (sh_ < 64) ? hi_ : lo_;                                        \
    W2_ = ((sh_ < 64) ? 0ull : hi_) | ((ull)f2bf(xx) << 48);             \
  }                                                                      \
  {                                                                      \
    float xx = (XV).y;                                                   \
    float u_  = fmaf(xx, 4.0f, 7.0f);                                    \
    float fm_ = floorf(u_);                                              \
    int   mi_ = (int)fm_;                                                \
    float t_  = u_ - fm_;                                                \
    float s_  = 1.0f - t_;                                               \
    float t2_ = t_ * t_, t3_ = t2_ * t_;                                 \
    float w0_ = (s_ * s_ * s_) * (1.0f / 6.0f);                          \
    float w3_ = t3_ * (1.0f / 6.0f);                                     \
    float w1_ = fmaf(0.5f, t3_, 2.0f / 3.0f) - t2_;                      \
    float w2_ = 1.0f - w0_ - w1_ - w3_;                                  \
    unsigned int p01_, p23_;                                             \
    asm("v_cvt_pk_bf16_f32 %0, %1, %2" : "=v"(p01_) : "v"(w0_), "v"(w1_)); \
    asm("v_cvt_pk_bf16_f32 %0, %1, %2" : "=v"(p23_) : "v"(w2_), "v"(w3_)); \
    ull W64_ = (ull)p01_ | ((ull)p23_ << 32);                            \
    int sh_ = (mi_ - 3) << 4;                                            \
    int a_  = sh_ & 63;                                                  \
    ull lo_ = W64_ << a_;                                                \
    ull hi_ = a_ ? (W64_ >> (64 - a_)) : 0ull;                           \
    W3_ = (sh_ < 64) ? lo_ : 0ull;                                       \
    W4_ = (sh_ < 64) ? hi_ : lo_;                                        \
    W5_ = ((sh_ < 64) ? 0ull : hi_) | ((ull)f2bf(xx) << 48);             \
  }                                                                      \
} while (0)

// ---- kernel 2: fused GEMM, 256x256 tile, k-quarter split, 128x64 waves ------
// R11 structure; tile body reordered: basis VALU after kstep-0 reads, A-writes
// after ALL ds_reads (sched_barrier-pinned) so no MFMA lgkm wait covers them.
__global__ __launch_bounds__(THREADS, 2) void kan_gemm(
    const float* __restrict__ x,             // [BATCH][INF]
    const us* __restrict__ WtT,              // tiled B
    float* __restrict__ P)                   // partials [4][BATCH][OUTF]
{
  // A dbuf (2) + B tribuf (3), each [gran6][256][8] = 24 KB -> 120 KB
  __shared__ alignas(16) us smem[5 * TSZ];

  const int tid  = threadIdx.x;
  const int lane = tid & 63;
  const int wid  = tid >> 6;              // 0..7
  const int wm   = (wid >> 2) * 128;      // 2 row groups of 128
  const int wn   = (wid & 3) * 64;        // 4 col groups of 64
  const int lo   = lane & 31;
  const int lh   = lane >> 5;
  const int b    = (int)blockIdx.x;       // 0..255
  const int bn   = b & 3;
  const int kq   = (b >> 2) & 3;          // k-quarter
  const int bm   = b >> 4;                // 0..15

  // A-build mapping: thread -> (row r, feature pair fp)
  const int r   = tid & 255;
  const int fp  = tid >> 8;               // 0 or 1
  const int g0A = fp * 3;
  const float* xrow = x + (size_t)(bm * BM + r) * INF + kq * 256 + fp * 2;

  us* Acur = smem;
  us* Aalt = smem + TSZ;
  us* Bcur = smem + 2 * TSZ;
  us* Bnxt = smem + 3 * TSZ;
  us* Bnn  = smem + 4 * TSZ;

  f32x16 acc[4][2] = {};

  auto stageB = [&](int c, us* Bd) {
    const int ktG = kq * NT + c;
    const us* base = WtT + (size_t)(bn * 256 + ktG) * (6 * 256 * 8);
#pragma unroll
    for (int j = 0; j < 3; ++j) {
      int s = wid * 3 + j;                // chunk 0..23 (1 KB each)
      int g = s >> 2, h = s & 3;
      async_copy16(base + g * 2048 + h * 512 + lane * 8,
                   Bd + g * 2048 + h * 512);   // wave-uniform dest; HW adds lane*16
    }
  };

#define WRITEW(AD, W0_,W1_,W2_,W3_,W4_,W5_) do {                   \
    U2* p_ = reinterpret_cast<U2*>(AD);                            \
    U2 u0_; u0_.x = W0_; u0_.y = W1_;                              \
    U2 u1_; u1_.x = W2_; u1_.y = W3_;                              \
    U2 u2_; u2_.x = W4_; u2_.y = W5_;                              \
    p_[(g0A + 0) * 256 + r] = u0_;                                 \
    p_[(g0A + 1) * 256 + r] = u1_;                                 \
    p_[(g0A + 2) * 256 + r] = u2_;                                 \
  } while (0)

#define READK(S, A0,A1,A2,A3,B0,B1) do {                           \
    const int kk_ = (S) * 2 + lh;                                  \
    A0 = *reinterpret_cast<const bf16x8*>(&Acur[(kk_ * 256 + wm +  0 + lo) * 8]); \
    A1 = *reinterpret_cast<const bf16x8*>(&Acur[(kk_ * 256 + wm + 32 + lo) * 8]); \
    A2 = *reinterpret_cast<const bf16x8*>(&Acur[(kk_ * 256 + wm + 64 + lo) * 8]); \
    A3 = *reinterpret_cast<const bf16x8*>(&Acur[(kk_ * 256 + wm + 96 + lo) * 8]); \
    B0 = *reinterpret_cast<const bf16x8*>(&Bcur[(kk_ * 256 + wn +  0 + lo) * 8]); \
    B1 = *reinterpret_cast<const bf16x8*>(&Bcur[(kk_ * 256 + wn + 32 + lo) * 8]); \
  } while (0)

#define MFMAK(A0,A1,A2,A3,B0,B1) do {                              \
    acc[0][0] = __builtin_amdgcn_mfma_f32_32x32x16_bf16(A0, B0, acc[0][0], 0, 0, 0); \
    acc[0][1] = __builtin_amdgcn_mfma_f32_32x32x16_bf16(A0, B1, acc[0][1], 0, 0, 0); \
    acc[1][0] = __builtin_amdgcn_mfma_f32_32x32x16_bf16(A1, B0, acc[1][0], 0, 0, 0); \
    acc[1][1] = __builtin_amdgcn_mfma_f32_32x32x16_bf16(A1, B1, acc[1][1], 0, 0, 0); \
    acc[2][0] = __builtin_amdgcn_mfma_f32_32x32x16_bf16(A2, B0, acc[2][0], 0, 0, 0); \
    acc[2][1] = __builtin_amdgcn_mfma_f32_32x32x16_bf16(A2, B1, acc[2][1], 0, 0, 0); \
    acc[3][0] = __builtin_amdgcn_mfma_f32_32x32x16_bf16(A3, B0, acc[3][0], 0, 0, 0); \
    acc[3][1] = __builtin_amdgcn_mfma_f32_32x32x16_bf16(A3, B1, acc[3][1], 0, 0, 0); \
  } while (0)

  // ---- prologue ----
  {
    float2 x0 = *reinterpret_cast<const float2*>(xrow);   // K-tile 0 feats
    ull W0, W1, W2, W3, W4, W5;
    BASIS2(x0, W0, W1, W2, W3, W4, W5);
    WRITEW(Acur, W0, W1, W2, W3, W4, W5);
    stageB(0, Bcur);                                      // 3 DMA
    stageB(1, Bnxt);                                      // 3 DMA
  }
  float2 xa = *reinterpret_cast<const float2*>(xrow + 4); // K-tile 1 feats
  PIPE_BARRIER();   // drains B0 + A0 writes; keeps {B1 DMAs, xa} in flight

  for (int c = 0; c < NT; ++c) {
    const int cf = (c + 2 < NT) ? (c + 2) : (NT - 1);

    float2 xb = *reinterpret_cast<const float2*>(xrow + cf * 4);   // vmem #1
    stageB(cf, Bnn);                                               // vmem #2-4

    ull W0, W1, W2, W3, W4, W5;
    bf16x8 a00, a01, a02, a03, b00, b01;
    bf16x8 a10, a11, a12, a13, b10, b11;
    bf16x8 a20, a21, a22, a23, b20, b21;

    READK(0, a00, a01, a02, a03, b00, b01);   // 6 ds_read
    BASIS2(xa, W0, W1, W2, W3, W4, W5);       // VALU under read-0 latency
    READK(1, a10, a11, a12, a13, b10, b11);   // 6 ds_read
    MFMAK(a00, a01, a02, a03, b00, b01);      // waits only reads-0
    READK(2, a20, a21, a22, a23, b20, b21);   // 6 ds_read
    MFMAK(a10, a11, a12, a13, b10, b11);
    __builtin_amdgcn_sched_barrier(0);        // pin: all reads precede writes
    WRITEW(Aalt, W0, W1, W2, W3, W4, W5);     // 3 ds_write (behind reads in queue)
    MFMAK(a20, a21, a22, a23, b20, b21);      // waits reads-2 (writes excluded)

    PIPE_BARRIER();

    us* t = Bcur; Bcur = Bnxt; Bnxt = Bnn; Bnn = t;
    t = Acur; Acur = Aalt; Aalt = t;
    xa = xb;
  }

  asm volatile("s_waitcnt vmcnt(0) lgkmcnt(0)" ::: "memory");

  // ---- epilogue: C/D row=(r&3)+8*(r>>2)+4*lh, col=lo (verified R4/R7/R8) ----
  float* dst = P + (size_t)kq * PART_FLOATS;
#pragma unroll
  for (int f = 0; f < 4; ++f) {
#pragma unroll
    for (int rr = 0; rr < 16; ++rr) {
      int row = bm * BM + wm + f * 32 + (rr & 3) + 8 * (rr >> 2) + 4 * lh;
      float* orow = dst + (size_t)row * OUTF + bn * BN + wn + lo;
#pragma unroll
      for (int n = 0; n < 2; ++n)
        orow[n * 32] = acc[f][n][rr];
    }
  }
}

// ---- kernel 3: out = (p0+p1)+(p2+p3), fixed order -> deterministic ----------
__global__ __launch_bounds__(256) void kan_reduce4(
    float4* __restrict__ out, const float4* __restrict__ p)
{
  size_t i = (size_t)blockIdx.x * 256 + threadIdx.x;   // 0..1048575
  const size_t Q = PART_FLOATS / 4;
  float4 a = p[i], bq = p[i + Q], c = p[i + 2 * Q], d = p[i + 3 * Q];
  float4 o;
  o.x = (a.x + bq.x) + (c.x + d.x);
  o.y = (a.y + bq.y) + (c.y + d.y);
  o.z = (a.z + bq.z) + (c.z + d.z);
  o.w = (a.w + bq.w) + (c.w + d.w);
  out[i] = o;
}

// ======================= fallback path (R8-class, proven) ====================
#define FB_BUFSZ (6*128*8)

__global__ __launch_bounds__(256) void kan_build_wt(
    const float* __restrict__ sw, const float* __restrict__ bw,
    us* __restrict__ Wt)
{
  int idx = blockIdx.x * 256 + threadIdx.x;
  int o = idx >> 10;
  int i = idx & 1023;
  const float* s = sw + (size_t)(o * 1024 + i) * 11;
  us v[12];
#pragma unroll
  for (int l = 0; l < 11; ++l) v[l] = f2bf(s[l]);
  v[11] = f2bf(bw[o * 1024 + i]);
  us* d = Wt + (size_t)o * KTOT + i * 12;
  *reinterpret_cast<ushort4*>(d + 0) = make_ushort4(v[0], v[1], v[2],  v[3]);
  *reinterpret_cast<ushort4*>(d + 4) = make_ushort4(v[4], v[5], v[6],  v[7]);
  *reinterpret_cast<ushort4*>(d + 8) = make_ushort4(v[8], v[9], v[10], v[11]);
}

__global__ __launch_bounds__(512, 4) void kan_gemm_fb(
    const float* __restrict__ x, const us* __restrict__ Wt,
    float* __restrict__ out)
{
  __shared__ alignas(16) us smem[5 * FB_BUFSZ];
  const int tid  = threadIdx.x;
  const int lane = tid & 63;
  const int wid  = tid >> 6;
  const int wm   = (wid >> 2) * 64;
  const int wn   = (wid & 3) * 32;
  const int lo   = lane & 31;
  const int lh   = lane >> 5;
  const int idx  = (int)blockIdx.x;
  const int bn   = idx & 7;
  const int kh   = (idx >> 3) & 1;
  const int bm   = idx >> 4;
  const bool builder = (tid < 256);
  const bool stager  = (wid >= 4);
  const int ab  = tid & 127;
  const int ai0 = ((tid >> 7) & 1) << 1;
  const float* xrow = x + (size_t)(bm * 128 + ab) * INF + kh * 512 + ai0;
  const size_t kbase = (size_t)kh * (KTOT / 2);

  us* Bcur = smem;            us* Bnxt = smem + FB_BUFSZ;
  us* Bnn  = smem + 2 * FB_BUFSZ;
  us* Acur = smem + 3 * FB_BUFSZ; us* Aalt = smem + 4 * FB_BUFSZ;
  f32x16 acc[2] = {};

  auto stageB = [&](int c, us* Bd) {
    const int wq = wid - 4;
#pragma unroll
    for (int qq = 0; qq < 3; ++qq) {
      int G  = (wq * 3 + qq) * 64 + lane;
      int kk = G >> 7;
      int oo = G & 127;
      const us* src = Wt + (size_t)(bn * 128 + oo) * KTOT + kbase + c * 48 + kk * 8;
      async_copy16(src, Bd + (wq * 3 + qq) * 512);
    }
  };
  auto buildA = [&](float2 xv, us* Ad) {
    ull W[6];
    basis12(xv.x, W + 0);
    basis12(xv.y, W + 3);
    U2* p = reinterpret_cast<U2*>(Ad);
    const int g0 = (ai0 >> 1) * 3;
    U2 u0; u0.x = W[0]; u0.y = W[1];
    U2 u1; u1.x = W[2]; u1.y = W[3];
    U2 u2; u2.x = W[4]; u2.y = W[5];
    p[(g0 + 0) * 128 + ab] = u0;
    p[(g0 + 1) * 128 + ab] = u1;
    p[(g0 + 2) * 128 + ab] = u2;
  };

  float2 xa = make_float2(0.f, 0.f);
  if (builder) {
    float2 x0v = *reinterpret_cast<const float2*>(xrow);
    buildA(x0v, Acur);
    xa = *reinterpret_cast<const float2*>(xrow + 4);
  }
  if (stager) { stageB(0, Bcur); stageB(1, Bnxt); }
  asm volatile("s_waitcnt vmcnt(3) lgkmcnt(0)" ::: "memory");
  __builtin_amdgcn_s_barrier();

  for (int c = 0; c < 128; ++c) {
    int cf = (c + 2 < 128) ? (c + 2) : 127;
    float2 xb = xa;
    if (builder) {
      xb = *reinterpret_cast<const float2*>(xrow + cf * 4);
      buildA(xa, Aalt);
    }
    if (stager) stageB(cf, Bnn);
#pragma unroll
    for (int s = 0; s < 3; ++s) {
      const int kk = s * 2 + lh;
      bf16x8 a0 = *reinterpret_cast<const bf16x8*>(&Acur[(kk * 128 + wm + lo) * 8]);
      bf16x8 a1 = *reinterpret_cast<const bf16x8*>(&Acur[(kk * 128 + wm + 32 + lo) * 8]);
      bf16x8 b0 = *reinterpret_cast<const bf16x8*>(&Bcur[(kk * 128 + wn + lo) * 8]);
      acc[0] = __builtin_amdgcn_mfma_f32_32x32x16_bf16(a0, b0, acc[0], 0, 0, 0);
      acc[1] = __builtin_amdgcn_mfma_f32_32x32x16_bf16(a1, b0, acc[1], 0, 0, 0);
    }
    asm volatile("s_waitcnt vmcnt(3) lgkmcnt(0)" ::: "memory");
    __builtin_amdgcn_s_barrier();
    us* t = Bcur; Bcur = Bnxt; Bnxt = Bnn; Bnn = t;
    t = Acur; Acur = Aalt; Aalt = t;
    xa = xb;
  }
  asm volatile("s_waitcnt vmcnt(0) lgkmcnt(0)" ::: "memory");
#pragma unroll
  for (int mf = 0; mf < 2; ++mf)
#pragma unroll
    for (int r2 = 0; r2 < 16; ++r2) {
      int row = bm * 128 + wm + mf * 32 + (r2 & 3) + 8 * (r2 >> 2) + 4 * lh;
      atomicAdd(out + (size_t)row * OUTF + bn * 128 + wn + lo, acc[mf][r2]);
    }
}

// =============================================================================
extern "C" void kernel_launch(void* const* d_in, const int* in_sizes, int n_in,
                              void* d_out, int out_size, void* d_ws, size_t ws_size,
                              hipStream_t stream) {
  const float* x  = (const float*)d_in[0];   // [4096][1024]
  const float* bw = (const float*)d_in[1];   // [1024][1024]
  const float* sw = (const float*)d_in[2];   // [1024][1024][11]
  float* out = (float*)d_out;

  if (ws_size >= WTT_BYTES + 4 * OUT_BYTES) {
    us* WtT  = (us*)d_ws;
    float* P = (float*)((char*)d_ws + WTT_BYTES);
    kan_build_wtT<<<2048, 256, 0, stream>>>(sw, bw, WtT);
    kan_gemm<<<256, THREADS, 0, stream>>>(x, WtT, P);
    kan_reduce4<<<(int)(PART_FLOATS / 4 / 256), 256, 0, stream>>>(
        (float4*)out, (const float4*)P);
  } else if (ws_size >= WTT_BYTES) {
    us* Wt = (us*)d_ws;
    kan_build_wt<<<(OUTF * INF) / 256, 256, 0, stream>>>(sw, bw, Wt);
    hipMemsetAsync(d_out, 0, OUT_BYTES, stream);
    kan_gemm_fb<<<512, 512, 0, stream>>>(x, Wt, out);
  }
}

// Round 14
// 146.596 us; speedup vs baseline: 1.3123x; 1.0966x over previous
//
#include <hip/hip_runtime.h>
#include <hip/hip_bf16.h>
#include <cstdint>

#define BATCH 4096
#define INF   1024
#define OUTF  1024
#define LCH   12
#define KTOT  (INF*LCH)       // 12288
#define BM    256
#define BN    256
#define BK    48              // 4 features per K-tile
#define NT    64              // K-tiles per k-quarter
#define THREADS 512
#define TSZ   (6*256*8)       // 12288 us = 24 KB per tile buffer (A or B)

#define WTT_BYTES ((size_t)OUTF * KTOT * 2)            // 25165824
#define PART_FLOATS ((size_t)BATCH * OUTF)             // 4194304
#define PQ_U32   (PART_FLOATS / 2)                     // 2097152 u32 per quarter
#define P_BYTES  ((size_t)4 * PQ_U32 * 4)              // 33554432
#define OUT_BYTES (PART_FLOATS * 4)                    // 16777216

typedef __bf16 bf16x8 __attribute__((ext_vector_type(8)));
typedef float  f32x16 __attribute__((ext_vector_type(16)));
typedef unsigned long long ull;
typedef unsigned short us;

struct alignas(16) U2 { ull x, y; };

__device__ __forceinline__ us f2bf(float f) {
  unsigned int u = __builtin_bit_cast(unsigned int, f);
  u += 0x7FFFu + ((u >> 16) & 1u);
  return (us)(u >> 16);
}

__device__ __forceinline__ void async_copy16(const void* g, void* l) {
  __builtin_amdgcn_global_load_lds(
      (const __attribute__((address_space(1))) unsigned int*)g,
      (__attribute__((address_space(3))) unsigned int*)l,
      16, 0, 0);
}

// keep the newest 4 VMEM ops (this iter's x-load + 3 B-DMAs) in flight;
// drain everything older + all LDS ops, then block barrier.
// INVARIANT: exactly 4 intended VMEM ops per iteration, no compiler-generated
// VMEM (no scratch spills) — keep all loop state in named scalars.
#define PIPE_BARRIER() do {                                        \
  asm volatile("s_waitcnt vmcnt(4) lgkmcnt(0)" ::: "memory");      \
  __builtin_amdgcn_sched_barrier(0);                               \
  __builtin_amdgcn_s_barrier();                                    \
  __builtin_amdgcn_sched_barrier(0);                               \
} while (0)

// 12 bf16 channels (11 spline + base/x) for one feature value (scalar path)
__device__ __forceinline__ void basis12(float xx, ull W[3]) {
  float u  = fmaf(xx, 4.0f, 7.0f);       // in (3,11); x in (-1,1)
  float fm = floorf(u);
  int   mi = (int)fm;                    // 3..10
  float t  = u - fm;
  float s  = 1.0f - t;
  float t2 = t * t, t3 = t2 * t;
  float w0 = (s * s * s) * (1.0f / 6.0f);
  float w3 = t3 * (1.0f / 6.0f);
  float w1 = fmaf(0.5f, t3, 2.0f / 3.0f) - t2;
  float w2 = 1.0f - w0 - w1 - w3;
  int ls = mi - 3;                       // 0..7
  ull W64 = (ull)f2bf(w0)
          | ((ull)f2bf(w1) << 16)
          | ((ull)f2bf(w2) << 32)
          | ((ull)f2bf(w3) << 48);
  int sh = ls << 4;                      // 0..112
  int a  = sh & 63;
  ull lop  = W64 << a;
  ull hip_ = a ? (W64 >> (64 - a)) : 0ull;
  W[0] = (sh < 64) ? lop : 0ull;
  W[1] = (sh < 64) ? hip_ : lop;
  W[2] = ((sh < 64) ? 0ull : hip_) | ((ull)f2bf(xx) << 48); // slot 11 = x
}

// ---- kernel 1: weights -> tiled WtT[bn4][ktG256][gran6][col256][8] bf16 -----
__global__ __launch_bounds__(256) void kan_build_wtT(
    const float* __restrict__ sw,        // [OUTF][INF][11]
    const float* __restrict__ bw,        // [OUTF][INF]
    us* __restrict__ WtT)
{
  int t   = blockIdx.x * 256 + threadIdx.x;   // 0..524287
  int col = t & 255;
  int q   = t >> 8;                           // 0..2047
  int fp  = q & 1;                            // feature pair in tile
  int ktG = (q >> 1) & 255;                   // global K-tile (4 feats)
  int bn  = q >> 9;                           // 0..3
  int o   = bn * 256 + col;
  int i0  = ktG * 4 + fp * 2;                 // even -> 8B-aligned f32 rows

  // 22 consecutive floats as 11 float2 (8B-aligned since i0 even)
  const float2* s2 = reinterpret_cast<const float2*>(
      sw + (size_t)(o * 1024 + i0) * 11);
  float2 sv[11];
#pragma unroll
  for (int l = 0; l < 11; ++l) sv[l] = s2[l];
  float2 bv = *reinterpret_cast<const float2*>(bw + (size_t)o * 1024 + i0);

  us v[24];
#pragma unroll
  for (int l = 0; l < 11; ++l) {
    int m0 = l;          // feature 0 channel l = flat float l
    int m1 = 11 + l;     // feature 1 channel l = flat float 11+l
    float f0 = (m0 & 1) ? sv[m0 >> 1].y : sv[m0 >> 1].x;
    float f1 = (m1 & 1) ? sv[m1 >> 1].y : sv[m1 >> 1].x;
    v[l]      = f2bf(f0);
    v[12 + l] = f2bf(f1);
  }
  v[11] = f2bf(bv.x);
  v[23] = f2bf(bv.y);

  int g0 = fp * 3;
  us* base = WtT + (size_t)(bn * 256 + ktG) * (6 * 256 * 8);
  U2* p = reinterpret_cast<U2*>(base);
#pragma unroll
  for (int j = 0; j < 3; ++j) {
    U2 u;
    const us* w = v + j * 8;
    u.x = (ull)w[0] | ((ull)w[1] << 16) | ((ull)w[2] << 32) | ((ull)w[3] << 48);
    u.y = (ull)w[4] | ((ull)w[5] << 16) | ((ull)w[6] << 32) | ((ull)w[7] << 48);
    p[(g0 + j) * 256 + col] = u;
  }
}

// basis for 2 features -> 6 named 64-bit words (all-static, cvt_pk packed)
#define BASIS2(XV, W0_,W1_,W2_,W3_,W4_,W5_) do {                         \
  {                                                                      \
    float xx = (XV).x;                                                   \
    float u_  = fmaf(xx, 4.0f, 7.0f);                                    \
    float fm_ = floorf(u_);                                              \
    int   mi_ = (int)fm_;                                                \
    float t_  = u_ - fm_;                                                \
    float s_  = 1.0f - t_;                                               \
    float t2_ = t_ * t_, t3_ = t2_ * t_;                                 \
    float w0_ = (s_ * s_ * s_) * (1.0f / 6.0f);                          \
    float w3_ = t3_ * (1.0f / 6.0f);                                     \
    float w1_ = fmaf(0.5f, t3_, 2.0f / 3.0f) - t2_;                      \
    float w2_ = 1.0f - w0_ - w1_ - w3_;                                  \
    unsigned int p01_, p23_;                                             \
    asm("v_cvt_pk_bf16_f32 %0, %1, %2" : "=v"(p01_) : "v"(w0_), "v"(w1_)); \
    asm("v_cvt_pk_bf16_f32 %0, %1, %2" : "=v"(p23_) : "v"(w2_), "v"(w3_)); \
    ull W64_ = (ull)p01_ | ((ull)p23_ << 32);                            \
    int sh_ = (mi_ - 3) << 4;                                            \
    int a_  = sh_ & 63;                                                  \
    ull lo_ = W64_ << a_;                                                \
    ull hi_ = a_ ? (W64_ >> (64 - a_)) : 0ull;                           \
    W0_ = (sh_ < 64) ? lo_ : 0ull;                                       \
    W1_ = (sh_ < 64) ? hi_ : lo_;                                        \
    W2_ = ((sh_ < 64) ? 0ull : hi_) | ((ull)f2bf(xx) << 48);             \
  }                                                                      \
  {                                                                      \
    float xx = (XV).y;                                                   \
    float u_  = fmaf(xx, 4.0f, 7.0f);                                    \
    float fm_ = floorf(u_);                                              \
    int   mi_ = (int)fm_;                                                \
    float t_  = u_ - fm_;                                                \
    float s_  = 1.0f - t_;                                               \
    float t2_ = t_ * t_, t3_ = t2_ * t_;                                 \
    float w0_ = (s_ * s_ * s_) * (1.0f / 6.0f);                          \
    float w3_ = t3_ * (1.0f / 6.0f);                                     \
    float w1_ = fmaf(0.5f, t3_, 2.0f / 3.0f) - t2_;                      \
    float w2_ = 1.0f - w0_ - w1_ - w3_;                                  \
    unsigned int p01_, p23_;                                             \
    asm("v_cvt_pk_bf16_f32 %0, %1, %2" : "=v"(p01_) : "v"(w0_), "v"(w1_)); \
    asm("v_cvt_pk_bf16_f32 %0, %1, %2" : "=v"(p23_) : "v"(w2_), "v"(w3_)); \
    ull W64_ = (ull)p01_ | ((ull)p23_ << 32);                            \
    int sh_ = (mi_ - 3) << 4;                                            \
    int a_  = sh_ & 63;                                                  \
    ull lo_ = W64_ << a_;                                                \
    ull hi_ = a_ ? (W64_ >> (64 - a_)) : 0ull;                           \
    W3_ = (sh_ < 64) ? lo_ : 0ull;                                       \
    W4_ = (sh_ < 64) ? hi_ : lo_;                                        \
    W5_ = ((sh_ < 64) ? 0ull : hi_) | ((ull)f2bf(xx) << 48);             \
  }                                                                      \
} while (0)

// ---- kernel 2: fused GEMM, 256x256 tile, k-quarter split, 128x64 waves ------
__global__ __launch_bounds__(THREADS, 2) void kan_gemm(
    const float* __restrict__ x,             // [BATCH][INF]
    const us* __restrict__ WtT,              // tiled B
    unsigned int* __restrict__ P)            // packed-bf16 partials [4][4096][512]
{
  // A dbuf (2) + B tribuf (3), each [gran6][256][8] = 24 KB -> 120 KB
  __shared__ alignas(16) us smem[5 * TSZ];

  const int tid  = threadIdx.x;
  const int lane = tid & 63;
  const int wid  = tid >> 6;              // 0..7
  const int wm   = (wid >> 2) * 128;      // 2 row groups of 128
  const int wn   = (wid & 3) * 64;        // 4 col groups of 64
  const int lo   = lane & 31;
  const int lh   = lane >> 5;
  const int b    = (int)blockIdx.x;       // 0..255
  const int bn   = b & 3;
  const int kq   = (b >> 2) & 3;          // k-quarter
  const int bm   = b >> 4;                // 0..15

  // A-build mapping: thread -> (row r, feature pair fp)
  const int r   = tid & 255;
  const int fp  = tid >> 8;               // 0 or 1
  const int g0A = fp * 3;
  const float* xrow = x + (size_t)(bm * BM + r) * INF + kq * 256 + fp * 2;

  us* Acur = smem;
  us* Aalt = smem + TSZ;
  us* Bcur = smem + 2 * TSZ;
  us* Bnxt = smem + 3 * TSZ;
  us* Bnn  = smem + 4 * TSZ;

  f32x16 acc[4][2] = {};

  auto stageB = [&](int c, us* Bd) {
    const int ktG = kq * NT + c;
    const us* base = WtT + (size_t)(bn * 256 + ktG) * (6 * 256 * 8);
#pragma unroll
    for (int j = 0; j < 3; ++j) {
      int s = wid * 3 + j;                // chunk 0..23 (1 KB each)
      int g = s >> 2, h = s & 3;
      async_copy16(base + g * 2048 + h * 512 + lane * 8,
                   Bd + g * 2048 + h * 512);   // wave-uniform dest; HW adds lane*16
    }
  };

#define WRITEW(AD, W0_,W1_,W2_,W3_,W4_,W5_) do {                   \
    U2* p_ = reinterpret_cast<U2*>(AD);                            \
    U2 u0_; u0_.x = W0_; u0_.y = W1_;                              \
    U2 u1_; u1_.x = W2_; u1_.y = W3_;                              \
    U2 u2_; u2_.x = W4_; u2_.y = W5_;                              \
    p_[(g0A + 0) * 256 + r] = u0_;                                 \
    p_[(g0A + 1) * 256 + r] = u1_;                                 \
    p_[(g0A + 2) * 256 + r] = u2_;                                 \
  } while (0)

#define READK(S, A0,A1,A2,A3,B0,B1) do {                           \
    const int kk_ = (S) * 2 + lh;                                  \
    A0 = *reinterpret_cast<const bf16x8*>(&Acur[(kk_ * 256 + wm +  0 + lo) * 8]); \
    A1 = *reinterpret_cast<const bf16x8*>(&Acur[(kk_ * 256 + wm + 32 + lo) * 8]); \
    A2 = *reinterpret_cast<const bf16x8*>(&Acur[(kk_ * 256 + wm + 64 + lo) * 8]); \
    A3 = *reinterpret_cast<const bf16x8*>(&Acur[(kk_ * 256 + wm + 96 + lo) * 8]); \
    B0 = *reinterpret_cast<const bf16x8*>(&Bcur[(kk_ * 256 + wn +  0 + lo) * 8]); \
    B1 = *reinterpret_cast<const bf16x8*>(&Bcur[(kk_ * 256 + wn + 32 + lo) * 8]); \
  } while (0)

#define MFMAK(A0,A1,A2,A3,B0,B1) do {                              \
    acc[0][0] = __builtin_amdgcn_mfma_f32_32x32x16_bf16(A0, B0, acc[0][0], 0, 0, 0); \
    acc[0][1] = __builtin_amdgcn_mfma_f32_32x32x16_bf16(A0, B1, acc[0][1], 0, 0, 0); \
    acc[1][0] = __builtin_amdgcn_mfma_f32_32x32x16_bf16(A1, B0, acc[1][0], 0, 0, 0); \
    acc[1][1] = __builtin_amdgcn_mfma_f32_32x32x16_bf16(A1, B1, acc[1][1], 0, 0, 0); \
    acc[2][0] = __builtin_amdgcn_mfma_f32_32x32x16_bf16(A2, B0, acc[2][0], 0, 0, 0); \
    acc[2][1] = __builtin_amdgcn_mfma_f32_32x32x16_bf16(A2, B1, acc[2][1], 0, 0, 0); \
    acc[3][0] = __builtin_amdgcn_mfma_f32_32x32x16_bf16(A3, B0, acc[3][0], 0, 0, 0); \
    acc[3][1] = __builtin_amdgcn_mfma_f32_32x32x16_bf16(A3, B1, acc[3][1], 0, 0, 0); \
  } while (0)

  // ---- prologue ----
  {
    float2 x0 = *reinterpret_cast<const float2*>(xrow);   // K-tile 0 feats
    ull W0, W1, W2, W3, W4, W5;
    BASIS2(x0, W0, W1, W2, W3, W4, W5);
    WRITEW(Acur, W0, W1, W2, W3, W4, W5);
    stageB(0, Bcur);                                      // 3 DMA
    stageB(1, Bnxt);                                      // 3 DMA
  }
  float2 xa = *reinterpret_cast<const float2*>(xrow + 4); // K-tile 1 feats
  PIPE_BARRIER();   // drains B0 + A0 writes; keeps {B1 DMAs, xa} in flight

  for (int c = 0; c < NT; ++c) {
    const int cf = (c + 2 < NT) ? (c + 2) : (NT - 1);

    float2 xb = *reinterpret_cast<const float2*>(xrow + cf * 4);   // vmem #1
    stageB(cf, Bnn);                                               // vmem #2-4

    ull W0, W1, W2, W3, W4, W5;
    bf16x8 a00, a01, a02, a03, b00, b01;
    bf16x8 a10, a11, a12, a13, b10, b11;
    bf16x8 a20, a21, a22, a23, b20, b21;

    READK(0, a00, a01, a02, a03, b00, b01);   // 6 ds_read
    BASIS2(xa, W0, W1, W2, W3, W4, W5);       // VALU under read-0 latency
    READK(1, a10, a11, a12, a13, b10, b11);   // 6 ds_read
    MFMAK(a00, a01, a02, a03, b00, b01);      // waits only reads-0
    READK(2, a20, a21, a22, a23, b20, b21);   // 6 ds_read
    MFMAK(a10, a11, a12, a13, b10, b11);
    __builtin_amdgcn_sched_barrier(0);        // pin: all reads precede writes
    WRITEW(Aalt, W0, W1, W2, W3, W4, W5);     // 3 ds_write (behind reads in queue)
    MFMAK(a20, a21, a22, a23, b20, b21);      // waits reads-2 (writes excluded)

    PIPE_BARRIER();

    us* t = Bcur; Bcur = Bnxt; Bnxt = Bnn; Bnn = t;
    t = Acur; Acur = Aalt; Aalt = t;
    xa = xb;
  }

  asm volatile("s_waitcnt vmcnt(0) lgkmcnt(0)" ::: "memory");

  // ---- epilogue: pack col-pair (wn+lo, wn+32+lo) as 2xbf16 in one u32 ----
  // u-index per row: bn*128 + (wn>>1) + lo  in [0,512)
  unsigned int* dst = P + (size_t)kq * PQ_U32;
  const int ubase = bn * 128 + (wn >> 1) + lo;
#pragma unroll
  for (int f = 0; f < 4; ++f) {
#pragma unroll
    for (int rr = 0; rr < 16; ++rr) {
      int row = bm * BM + wm + f * 32 + (rr & 3) + 8 * (rr >> 2) + 4 * lh;
      unsigned int pk;
      asm("v_cvt_pk_bf16_f32 %0, %1, %2"
          : "=v"(pk) : "v"(acc[f][0][rr]), "v"(acc[f][1][rr]));
      dst[(size_t)row * 512 + ubase] = pk;
    }
  }
}

// ---- kernel 3: unpack 4 bf16-packed partials, fixed-order sum -> f32 out ----
__global__ __launch_bounds__(256) void kan_reduce4p(
    float* __restrict__ out, const uint4* __restrict__ P)
{
  size_t i = (size_t)blockIdx.x * 256 + threadIdx.x;   // 0..524287
  const size_t Q = PQ_U32 / 4;                         // uint4 per quarter
  uint4 a = P[i], b = P[i + Q], c = P[i + 2 * Q], d = P[i + 3 * Q];

  size_t u0  = i * 4;                 // first u32 index
  size_t row = u0 >> 9;
  int ur  = (int)(u0 & 511);          // multiple of 4
  int pq  = ur >> 7;                  // bn panel 0..3
  int sub = (ur >> 5) & 3;            // wn/64
  int lo0 = ur & 31;                  // multiple of 4
  int col0 = pq * 256 + sub * 64 + lo0;

  float4 vlo, vhi;
  {
    unsigned int ua[4] = {a.x, a.y, a.z, a.w};
    unsigned int ub[4] = {b.x, b.y, b.z, b.w};
    unsigned int uc[4] = {c.x, c.y, c.z, c.w};
    unsigned int ud[4] = {d.x, d.y, d.z, d.w};
    float* plo = &vlo.x;
    float* phi = &vhi.x;
#pragma unroll
    for (int j = 0; j < 4; ++j) {
      float la = __builtin_bit_cast(float, ua[j] << 16);
      float lb = __builtin_bit_cast(float, ub[j] << 16);
      float lc = __builtin_bit_cast(float, uc[j] << 16);
      float ld = __builtin_bit_cast(float, ud[j] << 16);
      float ha = __builtin_bit_cast(float, ua[j] & 0xffff0000u);
      float hb = __builtin_bit_cast(float, ub[j] & 0xffff0000u);
      float hc = __builtin_bit_cast(float, uc[j] & 0xffff0000u);
      float hd = __builtin_bit_cast(float, ud[j] & 0xffff0000u);
      plo[j] = (la + lb) + (lc + ld);   // fixed order -> deterministic
      phi[j] = (ha + hb) + (hc + hd);
    }
  }
  *reinterpret_cast<float4*>(out + row * 1024 + col0)      = vlo;
  *reinterpret_cast<float4*>(out + row * 1024 + col0 + 32) = vhi;
}

// ======================= fallback path (R8-class, proven) ====================
#define FB_BUFSZ (6*128*8)

__global__ __launch_bounds__(256) void kan_build_wt(
    const float* __restrict__ sw, const float* __restrict__ bw,
    us* __restrict__ Wt)
{
  int idx = blockIdx.x * 256 + threadIdx.x;
  int o = idx >> 10;
  int i = idx & 1023;
  const float* s = sw + (size_t)(o * 1024 + i) * 11;
  us v[12];
#pragma unroll
  for (int l = 0; l < 11; ++l) v[l] = f2bf(s[l]);
  v[11] = f2bf(bw[o * 1024 + i]);
  us* d = Wt + (size_t)o * KTOT + i * 12;
  *reinterpret_cast<ushort4*>(d + 0) = make_ushort4(v[0], v[1], v[2],  v[3]);
  *reinterpret_cast<ushort4*>(d + 4) = make_ushort4(v[4], v[5], v[6],  v[7]);
  *reinterpret_cast<ushort4*>(d + 8) = make_ushort4(v[8], v[9], v[10], v[11]);
}

__global__ __launch_bounds__(512, 4) void kan_gemm_fb(
    const float* __restrict__ x, const us* __restrict__ Wt,
    float* __restrict__ out)
{
  __shared__ alignas(16) us smem[5 * FB_BUFSZ];
  const int tid  = threadIdx.x;
  const int lane = tid & 63;
  const int wid  = tid >> 6;
  const int wm   = (wid >> 2) * 64;
  const int wn   = (wid & 3) * 32;
  const int lo   = lane & 31;
  const int lh   = lane >> 5;
  const int idx  = (int)blockIdx.x;
  const int bn   = idx & 7;
  const int kh   = (idx >> 3) & 1;
  const int bm   = idx >> 4;
  const bool builder = (tid < 256);
  const bool stager  = (wid >= 4);
  const int ab  = tid & 127;
  const int ai0 = ((tid >> 7) & 1) << 1;
  const float* xrow = x + (size_t)(bm * 128 + ab) * INF + kh * 512 + ai0;
  const size_t kbase = (size_t)kh * (KTOT / 2);

  us* Bcur = smem;            us* Bnxt = smem + FB_BUFSZ;
  us* Bnn  = smem + 2 * FB_BUFSZ;
  us* Acur = smem + 3 * FB_BUFSZ; us* Aalt = smem + 4 * FB_BUFSZ;
  f32x16 acc[2] = {};

  auto stageB = [&](int c, us* Bd) {
    const int wq = wid - 4;
#pragma unroll
    for (int qq = 0; qq < 3; ++qq) {
      int G  = (wq * 3 + qq) * 64 + lane;
      int kk = G >> 7;
      int oo = G & 127;
      const us* src = Wt + (size_t)(bn * 128 + oo) * KTOT + kbase + c * 48 + kk * 8;
      async_copy16(src, Bd + (wq * 3 + qq) * 512);
    }
  };
  auto buildA = [&](float2 xv, us* Ad) {
    ull W[6];
    basis12(xv.x, W + 0);
    basis12(xv.y, W + 3);
    U2* p = reinterpret_cast<U2*>(Ad);
    const int g0 = (ai0 >> 1) * 3;
    U2 u0; u0.x = W[0]; u0.y = W[1];
    U2 u1; u1.x = W[2]; u1.y = W[3];
    U2 u2; u2.x = W[4]; u2.y = W[5];
    p[(g0 + 0) * 128 + ab] = u0;
    p[(g0 + 1) * 128 + ab] = u1;
    p[(g0 + 2) * 128 + ab] = u2;
  };

  float2 xa = make_float2(0.f, 0.f);
  if (builder) {
    float2 x0v = *reinterpret_cast<const float2*>(xrow);
    buildA(x0v, Acur);
    xa = *reinterpret_cast<const float2*>(xrow + 4);
  }
  if (stager) { stageB(0, Bcur); stageB(1, Bnxt); }
  asm volatile("s_waitcnt vmcnt(3) lgkmcnt(0)" ::: "memory");
  __builtin_amdgcn_s_barrier();

  for (int c = 0; c < 128; ++c) {
    int cf = (c + 2 < 128) ? (c + 2) : 127;
    float2 xb = xa;
    if (builder) {
      xb = *reinterpret_cast<const float2*>(xrow + cf * 4);
      buildA(xa, Aalt);
    }
    if (stager) stageB(cf, Bnn);
#pragma unroll
    for (int s = 0; s < 3; ++s) {
      const int kk = s * 2 + lh;
      bf16x8 a0 = *reinterpret_cast<const bf16x8*>(&Acur[(kk * 128 + wm + lo) * 8]);
      bf16x8 a1 = *reinterpret_cast<const bf16x8*>(&Acur[(kk * 128 + wm + 32 + lo) * 8]);
      bf16x8 b0 = *reinterpret_cast<const bf16x8*>(&Bcur[(kk * 128 + wn + lo) * 8]);
      acc[0] = __builtin_amdgcn_mfma_f32_32x32x16_bf16(a0, b0, acc[0], 0, 0, 0);
      acc[1] = __builtin_amdgcn_mfma_f32_32x32x16_bf16(a1, b0, acc[1], 0, 0, 0);
    }
    asm volatile("s_waitcnt vmcnt(3) lgkmcnt(0)" ::: "memory");
    __builtin_amdgcn_s_barrier();
    us* t = Bcur; Bcur = Bnxt; Bnxt = Bnn; Bnn = t;
    t = Acur; Acur = Aalt; Aalt = t;
    xa = xb;
  }
  asm volatile("s_waitcnt vmcnt(0) lgkmcnt(0)" ::: "memory");
#pragma unroll
  for (int mf = 0; mf < 2; ++mf)
#pragma unroll
    for (int r2 = 0; r2 < 16; ++r2) {
      int row = bm * 128 + wm + mf * 32 + (r2 & 3) + 8 * (r2 >> 2) + 4 * lh;
      atomicAdd(out + (size_t)row * OUTF + bn * 128 + wn + lo, acc[mf][r2]);
    }
}

// =============================================================================
extern "C" void kernel_launch(void* const* d_in, const int* in_sizes, int n_in,
                              void* d_out, int out_size, void* d_ws, size_t ws_size,
                              hipStream_t stream) {
  const float* x  = (const float*)d_in[0];   // [4096][1024]
  const float* bw = (const float*)d_in[1];   // [1024][1024]
  const float* sw = (const float*)d_in[2];   // [1024][1024][11]
  float* out = (float*)d_out;

  if (ws_size >= WTT_BYTES + P_BYTES) {
    us* WtT = (us*)d_ws;
    unsigned int* P = (unsigned int*)((char*)d_ws + WTT_BYTES);
    kan_build_wtT<<<2048, 256, 0, stream>>>(sw, bw, WtT);
    kan_gemm<<<256, THREADS, 0, stream>>>(x, WtT, P);
    kan_reduce4p<<<(int)(PQ_U32 / 4 / 256), 256, 0, stream>>>(
        out, (const uint4*)P);
  } else if (ws_size >= WTT_BYTES) {
    us* Wt = (us*)d_ws;
    kan_build_wt<<<(OUTF * INF) / 256, 256, 0, stream>>>(sw, bw, Wt);
    hipMemsetAsync(d_out, 0, OUT_BYTES, stream);
    kan_gemm_fb<<<512, 512, 0, stream>>>(x, Wt, out);
  }
}

// Round 15
// 140.682 us; speedup vs baseline: 1.3675x; 1.0420x over previous
//
#include <hip/hip_runtime.h>
#include <hip/hip_bf16.h>
#include <cstdint>

#define BATCH 4096
#define INF   1024
#define OUTF  1024
#define LCH   12
#define KTOT  (INF*LCH)       // 12288
#define BM    256
#define BN    128
#define BK    48              // 4 features per K-tile
#define NT    64              // K-tiles per k-quarter
#define THREADS 512
#define ASZ   (6*256*8)       // 12288 us = 24 KB per A buffer
#define BSZ   (6*128*8)       // 6144 us  = 12 KB per B buffer

#define WTT_BYTES ((size_t)OUTF * KTOT * 2)            // 25165824
#define PART_FLOATS ((size_t)BATCH * OUTF)             // 4194304
#define PQ_U32   (PART_FLOATS / 2)                     // 2097152 u32 per quarter
#define P_BYTES  ((size_t)4 * PQ_U32 * 4)              // 33554432
#define OUT_BYTES (PART_FLOATS * 4)                    // 16777216

typedef __bf16 bf16x8 __attribute__((ext_vector_type(8)));
typedef float  f32x16 __attribute__((ext_vector_type(16)));
typedef unsigned long long ull;
typedef unsigned short us;

struct alignas(16) U2 { ull x, y; };

__device__ __forceinline__ us f2bf(float f) {
  unsigned int u = __builtin_bit_cast(unsigned int, f);
  u += 0x7FFFu + ((u >> 16) & 1u);
  return (us)(u >> 16);
}

__device__ __forceinline__ void async_copy16(const void* g, void* l) {
  __builtin_amdgcn_global_load_lds(
      (const __attribute__((address_space(1))) unsigned int*)g,
      (__attribute__((address_space(3))) unsigned int*)l,
      16, 0, 0);
}

// double-buffer barrier: drain ALL DMAs (this iter's stage for the next tile)
// + all LDS ops; keep only the newest VMEM (the x prefetch) in flight.
// Per-wave vmcnt -> non-uniform DMA counts across waves are fine.
#define PIPE_BARRIER() do {                                        \
  asm volatile("s_waitcnt vmcnt(1) lgkmcnt(0)" ::: "memory");      \
  __builtin_amdgcn_sched_barrier(0);                               \
  __builtin_amdgcn_s_barrier();                                    \
  __builtin_amdgcn_sched_barrier(0);                               \
} while (0)

// 12 bf16 channels (11 spline + base/x) for one feature value (scalar path)
__device__ __forceinline__ void basis12(float xx, ull W[3]) {
  float u  = fmaf(xx, 4.0f, 7.0f);       // in (3,11); x in (-1,1)
  float fm = floorf(u);
  int   mi = (int)fm;                    // 3..10
  float t  = u - fm;
  float s  = 1.0f - t;
  float t2 = t * t, t3 = t2 * t;
  float w0 = (s * s * s) * (1.0f / 6.0f);
  float w3 = t3 * (1.0f / 6.0f);
  float w1 = fmaf(0.5f, t3, 2.0f / 3.0f) - t2;
  float w2 = 1.0f - w0 - w1 - w3;
  int ls = mi - 3;                       // 0..7
  ull W64 = (ull)f2bf(w0)
          | ((ull)f2bf(w1) << 16)
          | ((ull)f2bf(w2) << 32)
          | ((ull)f2bf(w3) << 48);
  int sh = ls << 4;                      // 0..112
  int a  = sh & 63;
  ull lop  = W64 << a;
  ull hip_ = a ? (W64 >> (64 - a)) : 0ull;
  W[0] = (sh < 64) ? lop : 0ull;
  W[1] = (sh < 64) ? hip_ : lop;
  W[2] = ((sh < 64) ? 0ull : hip_) | ((ull)f2bf(xx) << 48); // slot 11 = x
}

// ---- kernel 1: weights -> tiled WtT[bn8][ktG256][gran6][col128][8] bf16 -----
__global__ __launch_bounds__(256) void kan_build_wtT(
    const float* __restrict__ sw,        // [OUTF][INF][11]
    const float* __restrict__ bw,        // [OUTF][INF]
    us* __restrict__ WtT)
{
  int t   = blockIdx.x * 256 + threadIdx.x;   // 0..524287
  int col = t & 127;
  int q   = t >> 7;                           // 0..4095
  int fp  = q & 1;                            // feature pair in tile
  int ktG = (q >> 1) & 255;                   // global K-tile (4 feats)
  int bn  = q >> 9;                           // 0..7
  int o   = bn * 128 + col;
  int i0  = ktG * 4 + fp * 2;                 // even -> 8B-aligned f32 rows

  // 22 consecutive floats as 11 float2 (8B-aligned since i0 even)
  const float2* s2 = reinterpret_cast<const float2*>(
      sw + (size_t)(o * 1024 + i0) * 11);
  float2 sv[11];
#pragma unroll
  for (int l = 0; l < 11; ++l) sv[l] = s2[l];
  float2 bv = *reinterpret_cast<const float2*>(bw + (size_t)o * 1024 + i0);

  us v[24];
#pragma unroll
  for (int l = 0; l < 11; ++l) {
    int m0 = l;          // feature 0 channel l
    int m1 = 11 + l;     // feature 1 channel l
    float f0 = (m0 & 1) ? sv[m0 >> 1].y : sv[m0 >> 1].x;
    float f1 = (m1 & 1) ? sv[m1 >> 1].y : sv[m1 >> 1].x;
    v[l]      = f2bf(f0);
    v[12 + l] = f2bf(f1);
  }
  v[11] = f2bf(bv.x);
  v[23] = f2bf(bv.y);

  int g0 = fp * 3;
  us* base = WtT + (size_t)(bn * 256 + ktG) * (6 * 128 * 8);
  U2* p = reinterpret_cast<U2*>(base);
#pragma unroll
  for (int j = 0; j < 3; ++j) {
    U2 u;
    const us* w = v + j * 8;
    u.x = (ull)w[0] | ((ull)w[1] << 16) | ((ull)w[2] << 32) | ((ull)w[3] << 48);
    u.y = (ull)w[4] | ((ull)w[5] << 16) | ((ull)w[6] << 32) | ((ull)w[7] << 48);
    p[(g0 + j) * 128 + col] = u;
  }
}

// basis for 2 features -> 6 named 64-bit words (all-static, cvt_pk packed)
#define BASIS2(XV, W0_,W1_,W2_,W3_,W4_,W5_) do {                         \
  {                                                                      \
    float xx = (XV).x;                                                   \
    float u_  = fmaf(xx, 4.0f, 7.0f);                                    \
    float fm_ = floorf(u_);                                              \
    int   mi_ = (int)fm_;                                                \
    float t_  = u_ - fm_;                                                \
    float s_  = 1.0f - t_;                                               \
    float t2_ = t_ * t_, t3_ = t2_ * t_;                                 \
    float w0_ = (s_ * s_ * s_) * (1.0f / 6.0f);                          \
    float w3_ = t3_ * (1.0f / 6.0f);                                     \
    float w1_ = fmaf(0.5f, t3_, 2.0f / 3.0f) - t2_;                      \
    float w2_ = 1.0f - w0_ - w1_ - w3_;                                  \
    unsigned int p01_, p23_;                                             \
    asm("v_cvt_pk_bf16_f32 %0, %1, %2" : "=v"(p01_) : "v"(w0_), "v"(w1_)); \
    asm("v_cvt_pk_bf16_f32 %0, %1, %2" : "=v"(p23_) : "v"(w2_), "v"(w3_)); \
    ull W64_ = (ull)p01_ | ((ull)p23_ << 32);                            \
    int sh_ = (mi_ - 3) << 4;                                            \
    int a_  = sh_ & 63;                                                  \
    ull lo_ = W64_ << a_;                                                \
    ull hi_ = a_ ? (W64_ >> (64 - a_)) : 0ull;                           \
    W0_ = (sh_ < 64) ? lo_ : 0ull;                                       \
    W1_ = (sh_ < 64) ? hi_ : lo_;                                        \
    W2_ = ((sh_ < 64) ? 0ull : hi_) | ((ull)f2bf(xx) << 48);             \
  }                                                                      \
  {                                                                      \
    float xx = (XV).y;                                                   \
    float u_  = fmaf(xx, 4.0f, 7.0f);                                    \
    float fm_ = floorf(u_);                                              \
    int   mi_ = (int)fm_;                                                \
    float t_  = u_ - fm_;                                                \
    float s_  = 1.0f - t_;                                               \
    float t2_ = t_ * t_, t3_ = t2_ * t_;                                 \
    float w0_ = (s_ * s_ * s_) * (1.0f / 6.0f);                          \
    float w3_ = t3_ * (1.0f / 6.0f);                                     \
    float w1_ = fmaf(0.5f, t3_, 2.0f / 3.0f) - t2_;                      \
    float w2_ = 1.0f - w0_ - w1_ - w3_;                                  \
    unsigned int p01_, p23_;                                             \
    asm("v_cvt_pk_bf16_f32 %0, %1, %2" : "=v"(p01_) : "v"(w0_), "v"(w1_)); \
    asm("v_cvt_pk_bf16_f32 %0, %1, %2" : "=v"(p23_) : "v"(w2_), "v"(w3_)); \
    ull W64_ = (ull)p01_ | ((ull)p23_ << 32);                            \
    int sh_ = (mi_ - 3) << 4;                                            \
    int a_  = sh_ & 63;                                                  \
    ull lo_ = W64_ << a_;                                                \
    ull hi_ = a_ ? (W64_ >> (64 - a_)) : 0ull;                           \
    W3_ = (sh_ < 64) ? lo_ : 0ull;                                       \
    W4_ = (sh_ < 64) ? hi_ : lo_;                                        \
    W5_ = ((sh_ < 64) ? 0ull : hi_) | ((ull)f2bf(xx) << 48);             \
  }                                                                      \
} while (0)

// ---- kernel 2: fused GEMM, 256x128 tile, k-quarter split, 64x64 waves -------
// 72 KB LDS -> 2 blocks/CU -> 4 waves/SIMD (the untested lever with good geom).
__global__ __launch_bounds__(THREADS, 4) void kan_gemm(
    const float* __restrict__ x,             // [BATCH][INF]
    const us* __restrict__ WtT,              // tiled B
    unsigned int* __restrict__ P)            // packed-bf16 partials [4][4096][512]
{
  // A dbuf (2x24K) + B dbuf (2x12K) = 73728 B
  __shared__ alignas(16) us smem[2 * ASZ + 2 * BSZ];

  const int tid  = threadIdx.x;
  const int lane = tid & 63;
  const int wid  = tid >> 6;              // 0..7
  const int wm   = (wid >> 1) * 64;       // 4 row groups of 64
  const int wn   = (wid & 1) * 64;        // 2 col groups of 64
  const int lo   = lane & 31;
  const int lh   = lane >> 5;
  const int b    = (int)blockIdx.x;       // 0..511
  const int bn   = b & 7;                 // panel == XCD id under RR dispatch
  const int kq   = (b >> 3) & 3;          // k-quarter
  const int bm   = b >> 5;                // 0..15

  // A-build mapping: thread -> (row r, feature pair fp)
  const int r   = tid & 255;
  const int fp  = tid >> 8;               // 0 or 1
  const int g0A = fp * 3;
  const float* xrow = x + (size_t)(bm * BM + r) * INF + kq * 256 + fp * 2;

  us* Acur = smem;
  us* Aalt = smem + ASZ;
  us* Bcur = smem + 2 * ASZ;
  us* Balt = smem + 2 * ASZ + BSZ;

  f32x16 acc[2][2] = {};

  // 12 chunks of 1 KB; waves 0..5 take 2 chunks each (non-uniform is OK:
  // vmcnt is per-wave and the barrier drains ALL DMAs).
  auto stageB = [&](int c, us* Bd) {
    if (wid < 6) {
      const int ktG = kq * NT + c;
      const us* base = WtT + (size_t)(bn * 256 + ktG) * (6 * 128 * 8);
#pragma unroll
      for (int j = 0; j < 2; ++j) {
        int ch = wid * 2 + j;             // 0..11
        int g = ch >> 1, h = ch & 1;
        async_copy16(base + g * 1024 + h * 512 + lane * 8,
                     Bd + g * 1024 + h * 512);   // wave-uniform dest
      }
    }
  };

#define WRITEW(AD, W0_,W1_,W2_,W3_,W4_,W5_) do {                   \
    U2* p_ = reinterpret_cast<U2*>(AD);                            \
    U2 u0_; u0_.x = W0_; u0_.y = W1_;                              \
    U2 u1_; u1_.x = W2_; u1_.y = W3_;                              \
    U2 u2_; u2_.x = W4_; u2_.y = W5_;                              \
    p_[(g0A + 0) * 256 + r] = u0_;                                 \
    p_[(g0A + 1) * 256 + r] = u1_;                                 \
    p_[(g0A + 2) * 256 + r] = u2_;                                 \
  } while (0)

#define READK(S, A0,A1,B0,B1) do {                                 \
    const int kk_ = (S) * 2 + lh;                                  \
    A0 = *reinterpret_cast<const bf16x8*>(&Acur[(kk_ * 256 + wm +  0 + lo) * 8]); \
    A1 = *reinterpret_cast<const bf16x8*>(&Acur[(kk_ * 256 + wm + 32 + lo) * 8]); \
    B0 = *reinterpret_cast<const bf16x8*>(&Bcur[(kk_ * 128 + wn +  0 + lo) * 8]); \
    B1 = *reinterpret_cast<const bf16x8*>(&Bcur[(kk_ * 128 + wn + 32 + lo) * 8]); \
  } while (0)

#define MFMAK(A0,A1,B0,B1) do {                                    \
    acc[0][0] = __builtin_amdgcn_mfma_f32_32x32x16_bf16(A0, B0, acc[0][0], 0, 0, 0); \
    acc[0][1] = __builtin_amdgcn_mfma_f32_32x32x16_bf16(A0, B1, acc[0][1], 0, 0, 0); \
    acc[1][0] = __builtin_amdgcn_mfma_f32_32x32x16_bf16(A1, B0, acc[1][0], 0, 0, 0); \
    acc[1][1] = __builtin_amdgcn_mfma_f32_32x32x16_bf16(A1, B1, acc[1][1], 0, 0, 0); \
  } while (0)

  // ---- prologue: DMAs first, x prefetch LAST (vmcnt(1) keeps it) ----
  stageB(0, Bcur);                                        // DMAs (oldest)
  {
    float2 x0 = *reinterpret_cast<const float2*>(xrow);   // consumed below
    ull W0, W1, W2, W3, W4, W5;
    BASIS2(x0, W0, W1, W2, W3, W4, W5);
    WRITEW(Acur, W0, W1, W2, W3, W4, W5);
  }
  float2 xa = *reinterpret_cast<const float2*>(xrow + 4); // newest VMEM
  PIPE_BARRIER();   // drains stage(0) + A0 writes; keeps xa in flight

  for (int c = 0; c < NT; ++c) {
    const int cf = (c + 2 < NT) ? (c + 2) : (NT - 1);

    stageB(c + 1 < NT ? c + 1 : NT - 1, Balt);                     // DMAs first
    float2 xb = *reinterpret_cast<const float2*>(xrow + cf * 4);   // newest VMEM

    ull W0, W1, W2, W3, W4, W5;
    bf16x8 a00, a01, b00, b01;
    bf16x8 a10, a11, b10, b11;
    bf16x8 a20, a21, b20, b21;

    READK(0, a00, a01, b00, b01);             // 4 ds_read
    BASIS2(xa, W0, W1, W2, W3, W4, W5);       // VALU under read-0 latency
    READK(1, a10, a11, b10, b11);
    MFMAK(a00, a01, b00, b01);                // waits only reads-0
    READK(2, a20, a21, b20, b21);
    MFMAK(a10, a11, b10, b11);
    __builtin_amdgcn_sched_barrier(0);        // pin: all reads precede writes
    WRITEW(Aalt, W0, W1, W2, W3, W4, W5);     // 3 ds_write
    MFMAK(a20, a21, b20, b21);

    PIPE_BARRIER();   // drains stage(c+1) + A(c+1) writes; keeps xb

    us* t = Bcur; Bcur = Balt; Balt = t;
    t = Acur; Acur = Aalt; Aalt = t;
    xa = xb;
  }

  asm volatile("s_waitcnt vmcnt(0) lgkmcnt(0)" ::: "memory");

  // ---- epilogue: pack col-pair (wn+lo, wn+32+lo); u = bn*64 + (wn>>1) + lo --
  unsigned int* dst = P + (size_t)kq * PQ_U32;
  const int ubase = bn * 64 + (wn >> 1) + lo;
#pragma unroll
  for (int f = 0; f < 2; ++f) {
#pragma unroll
    for (int rr = 0; rr < 16; ++rr) {
      int row = bm * BM + wm + f * 32 + (rr & 3) + 8 * (rr >> 2) + 4 * lh;
      unsigned int pk;
      asm("v_cvt_pk_bf16_f32 %0, %1, %2"
          : "=v"(pk) : "v"(acc[f][0][rr]), "v"(acc[f][1][rr]));
      dst[(size_t)row * 512 + ubase] = pk;
    }
  }
}

// ---- kernel 3: unpack 4 bf16-packed partials, fixed-order sum -> f32 out ----
// u decode: bn = u>>6, s = (u>>5)&1, lo = u&31; col = bn*128 + s*64 + lo (+32)
__global__ __launch_bounds__(256) void kan_reduce4p(
    float* __restrict__ out, const uint4* __restrict__ P)
{
  size_t i = (size_t)blockIdx.x * 256 + threadIdx.x;   // 0..524287
  const size_t Q = PQ_U32 / 4;                         // uint4 per quarter
  uint4 a = P[i], b = P[i + Q], c = P[i + 2 * Q], d = P[i + 3 * Q];

  size_t u0  = i * 4;                 // first u32 index
  size_t row = u0 >> 9;
  int ur   = (int)(u0 & 511);         // multiple of 4
  int col0 = (ur >> 6) * 128 + ((ur >> 5) & 1) * 64 + (ur & 31);

  float4 vlo, vhi;
  {
    unsigned int ua[4] = {a.x, a.y, a.z, a.w};
    unsigned int ub[4] = {b.x, b.y, b.z, b.w};
    unsigned int uc[4] = {c.x, c.y, c.z, c.w};
    unsigned int ud[4] = {d.x, d.y, d.z, d.w};
    float* plo = &vlo.x;
    float* phi = &vhi.x;
#pragma unroll
    for (int j = 0; j < 4; ++j) {
      float la = __builtin_bit_cast(float, ua[j] << 16);
      float lb = __builtin_bit_cast(float, ub[j] << 16);
      float lc = __builtin_bit_cast(float, uc[j] << 16);
      float ld = __builtin_bit_cast(float, ud[j] << 16);
      float ha = __builtin_bit_cast(float, ua[j] & 0xffff0000u);
      float hb = __builtin_bit_cast(float, ub[j] & 0xffff0000u);
      float hc = __builtin_bit_cast(float, uc[j] & 0xffff0000u);
      float hd = __builtin_bit_cast(float, ud[j] & 0xffff0000u);
      plo[j] = (la + lb) + (lc + ld);   // fixed order -> deterministic
      phi[j] = (ha + hb) + (hc + hd);
    }
  }
  *reinterpret_cast<float4*>(out + row * 1024 + col0)      = vlo;
  *reinterpret_cast<float4*>(out + row * 1024 + col0 + 32) = vhi;
}

// ======================= fallback path (R8-class, proven) ====================
#define FB_BUFSZ (6*128*8)

__global__ __launch_bounds__(256) void kan_build_wt(
    const float* __restrict__ sw, const float* __restrict__ bw,
    us* __restrict__ Wt)
{
  int idx = blockIdx.x * 256 + threadIdx.x;
  int o = idx >> 10;
  int i = idx & 1023;
  const float* s = sw + (size_t)(o * 1024 + i) * 11;
  us v[12];
#pragma unroll
  for (int l = 0; l < 11; ++l) v[l] = f2bf(s[l]);
  v[11] = f2bf(bw[o * 1024 + i]);
  us* d = Wt + (size_t)o * KTOT + i * 12;
  *reinterpret_cast<ushort4*>(d + 0) = make_ushort4(v[0], v[1], v[2],  v[3]);
  *reinterpret_cast<ushort4*>(d + 4) = make_ushort4(v[4], v[5], v[6],  v[7]);
  *reinterpret_cast<ushort4*>(d + 8) = make_ushort4(v[8], v[9], v[10], v[11]);
}

__global__ __launch_bounds__(512, 4) void kan_gemm_fb(
    const float* __restrict__ x, const us* __restrict__ Wt,
    float* __restrict__ out)
{
  __shared__ alignas(16) us smem[5 * FB_BUFSZ];
  const int tid  = threadIdx.x;
  const int lane = tid & 63;
  const int wid  = tid >> 6;
  const int wm   = (wid >> 2) * 64;
  const int wn   = (wid & 3) * 32;
  const int lo   = lane & 31;
  const int lh   = lane >> 5;
  const int idx  = (int)blockIdx.x;
  const int bn   = idx & 7;
  const int kh   = (idx >> 3) & 1;
  const int bm   = idx >> 4;
  const bool builder = (tid < 256);
  const bool stager  = (wid >= 4);
  const int ab  = tid & 127;
  const int ai0 = ((tid >> 7) & 1) << 1;
  const float* xrow = x + (size_t)(bm * 128 + ab) * INF + kh * 512 + ai0;
  const size_t kbase = (size_t)kh * (KTOT / 2);

  us* Bcur = smem;            us* Bnxt = smem + FB_BUFSZ;
  us* Bnn  = smem + 2 * FB_BUFSZ;
  us* Acur = smem + 3 * FB_BUFSZ; us* Aalt = smem + 4 * FB_BUFSZ;
  f32x16 acc[2] = {};

  auto stageB = [&](int c, us* Bd) {
    const int wq = wid - 4;
#pragma unroll
    for (int qq = 0; qq < 3; ++qq) {
      int G  = (wq * 3 + qq) * 64 + lane;
      int kk = G >> 7;
      int oo = G & 127;
      const us* src = Wt + (size_t)(bn * 128 + oo) * KTOT + kbase + c * 48 + kk * 8;
      async_copy16(src, Bd + (wq * 3 + qq) * 512);
    }
  };
  auto buildA = [&](float2 xv, us* Ad) {
    ull W[6];
    basis12(xv.x, W + 0);
    basis12(xv.y, W + 3);
    U2* p = reinterpret_cast<U2*>(Ad);
    const int g0 = (ai0 >> 1) * 3;
    U2 u0; u0.x = W[0]; u0.y = W[1];
    U2 u1; u1.x = W[2]; u1.y = W[3];
    U2 u2; u2.x = W[4]; u2.y = W[5];
    p[(g0 + 0) * 128 + ab] = u0;
    p[(g0 + 1) * 128 + ab] = u1;
    p[(g0 + 2) * 128 + ab] = u2;
  };

  float2 xa = make_float2(0.f, 0.f);
  if (builder) {
    float2 x0v = *reinterpret_cast<const float2*>(xrow);
    buildA(x0v, Acur);
    xa = *reinterpret_cast<const float2*>(xrow + 4);
  }
  if (stager) { stageB(0, Bcur); stageB(1, Bnxt); }
  asm volatile("s_waitcnt vmcnt(3) lgkmcnt(0)" ::: "memory");
  __builtin_amdgcn_s_barrier();

  for (int c = 0; c < 128; ++c) {
    int cf = (c + 2 < 128) ? (c + 2) : 127;
    float2 xb = xa;
    if (builder) {
      xb = *reinterpret_cast<const float2*>(xrow + cf * 4);
      buildA(xa, Aalt);
    }
    if (stager) stageB(cf, Bnn);
#pragma unroll
    for (int s = 0; s < 3; ++s) {
      const int kk = s * 2 + lh;
      bf16x8 a0 = *reinterpret_cast<const bf16x8*>(&Acur[(kk * 128 + wm + lo) * 8]);
      bf16x8 a1 = *reinterpret_cast<const bf16x8*>(&Acur[(kk * 128 + wm + 32 + lo) * 8]);
      bf16x8 b0 = *reinterpret_cast<const bf16x8*>(&Bcur[(kk * 128 + wn + lo) * 8]);
      acc[0] = __builtin_amdgcn_mfma_f32_32x32x16_bf16(a0, b0, acc[0], 0, 0, 0);
      acc[1] = __builtin_amdgcn_mfma_f32_32x32x16_bf16(a1, b0, acc[1], 0, 0, 0);
    }
    asm volatile("s_waitcnt vmcnt(3) lgkmcnt(0)" ::: "memory");
    __builtin_amdgcn_s_barrier();
    us* t = Bcur; Bcur = Bnxt; Bnxt = Bnn; Bnn = t;
    t = Acur; Acur = Aalt; Aalt = t;
    xa = xb;
  }
  asm volatile("s_waitcnt vmcnt(0) lgkmcnt(0)" ::: "memory");
#pragma unroll
  for (int mf = 0; mf < 2; ++mf)
#pragma unroll
    for (int r2 = 0; r2 < 16; ++r2) {
      int row = bm * 128 + wm + mf * 32 + (r2 & 3) + 8 * (r2 >> 2) + 4 * lh;
      atomicAdd(out + (size_t)row * OUTF + bn * 128 + wn + lo, acc[mf][r2]);
    }
}

// =============================================================================
extern "C" void kernel_launch(void* const* d_in, const int* in_sizes, int n_in,
                              void* d_out, int out_size, void* d_ws, size_t ws_size,
                              hipStream_t stream) {
  const float* x  = (const float*)d_in[0];   // [4096][1024]
  const float* bw = (const float*)d_in[1];   // [1024][1024]
  const float* sw = (const float*)d_in[2];   // [1024][1024][11]
  float* out = (float*)d_out;

  if (ws_size >= WTT_BYTES + P_BYTES) {
    us* WtT = (us*)d_ws;
    unsigned int* P = (unsigned int*)((char*)d_ws + WTT_BYTES);
    kan_build_wtT<<<2048, 256, 0, stream>>>(sw, bw, WtT);
    kan_gemm<<<512, THREADS, 0, stream>>>(x, WtT, P);
    kan_reduce4p<<<(int)(PQ_U32 / 4 / 256), 256, 0, stream>>>(
        out, (const uint4*)P);
  } else if (ws_size >= WTT_BYTES) {
    us* Wt = (us*)d_ws;
    kan_build_wt<<<(OUTF * INF) / 256, 256, 0, stream>>>(sw, bw, Wt);
    hipMemsetAsync(d_out, 0, OUT_BYTES, stream);
    kan_gemm_fb<<<512, 512, 0, stream>>>(x, Wt, out);
  }
}